// Round 6
// baseline (676.224 us; speedup 1.0000x reference)
//
#include <hip/hip_runtime.h>

#define Nn   4096
#define FINd 512
#define HIDd 256
#define NEd  131072

typedef unsigned short u16;
typedef __bf16 bf16x8 __attribute__((ext_vector_type(8)));
typedef float floatx4 __attribute__((ext_vector_type(4)));

// ---------------- bf16 helpers ----------------
__device__ __forceinline__ float bf2f(u16 u) {
  union { unsigned int i; float f; } v; v.i = ((unsigned int)u) << 16; return v.f;
}
__device__ __forceinline__ u16 f2bf(float f) {
  union { unsigned int i; float f; } v; v.f = f;
  unsigned int x = v.i;
  return (u16)((x + 0x7FFFu + ((x >> 16) & 1u)) >> 16);  // RNE
}

#define GLDS(gp, lp) __builtin_amdgcn_global_load_lds( \
    (__attribute__((address_space(1))) unsigned int*)(void*)(gp), \
    (__attribute__((address_space(3))) unsigned int*)(lp), 16, 0, 0)

// ---------------- private-LDS histogram -> slabs (no global atomics) ----------
__global__ __launch_bounds__(256) void hist_priv_k(const int* __restrict__ rows,
                                                   const int* __restrict__ cols,
                                                   int* __restrict__ slabs) {
  __shared__ int cnt[8192];
  const int t = threadIdx.x;
  for (int i = t; i < 8192; i += 256) cnt[i] = 0;
  __syncthreads();
  int base = blockIdx.x * 4096;
  for (int i = t; i < 4096; i += 256) {
    int e = base + i;
    atomicAdd(&cnt[rows[e]], 1);
    atomicAdd(&cnt[4096 + cols[e]], 1);
  }
  __syncthreads();
  int* out = slabs + blockIdx.x * 8192;
  for (int i = t; i < 8192; i += 256) out[i] = cnt[i];
}

// ---------------- scan (sum 32 slabs -> rp/cp) + dtype detect + zero fills ------
__global__ __launch_bounds__(1024) void scan2_k(const unsigned int* __restrict__ X,
                                                const int* __restrict__ slabs,
                                                int* __restrict__ rp, int* __restrict__ cp,
                                                int* __restrict__ rfill, int* __restrict__ cfill,
                                                int* __restrict__ flag) {
  __shared__ int part[1024];
  __shared__ int dcnt;
  const int t = threadIdx.x;
  if (t == 0) dcnt = 0;
  __syncthreads();
  int local = 0;
  for (int i = t; i < 4096; i += 1024) {
    unsigned e = (X[i] >> 7) & 0xFFu;
    if (e >= 100u && e <= 140u) local++;
  }
  if (local) atomicAdd(&dcnt, local);
  int base = t * 8, s = 0, loc[8];
  int csum[8];
#pragma unroll
  for (int j = 0; j < 8; ++j) csum[j] = 0;
  for (int sl = 0; sl < 32; ++sl) {
    const int* sp = slabs + sl * 8192 + base;
#pragma unroll
    for (int j = 0; j < 8; ++j) csum[j] += sp[j];
  }
#pragma unroll
  for (int j = 0; j < 8; ++j) { loc[j] = s; s += csum[j]; }
  part[t] = s;
  __syncthreads();
  if (t == 0) *flag = (dcnt > 2458) ? 1 : 0;
  for (int off = 1; off < 1024; off <<= 1) {
    int v = (t >= off) ? part[t - off] : 0;
    __syncthreads();
    part[t] += v;
    __syncthreads();
  }
  int excl = (t == 0) ? 0 : part[t - 1];
  int rtot = part[511];
  if (t < 512) {
#pragma unroll
    for (int j = 0; j < 8; ++j) rp[base + j] = excl + loc[j];
    if (t == 511) rp[4096] = rtot;
  } else {
    int cb = base - 4096;
    int ex2 = excl - rtot;
#pragma unroll
    for (int j = 0; j < 8; ++j) cp[cb + j] = ex2 + loc[j];
    if (t == 1023) cp[4096] = part[1023] - rtot;
  }
  for (int i = t; i < 4096; i += 1024) { rfill[i] = 0; cfill[i] = 0; }
}

// ---------------- converts/transposes + CSR/CSC scatter, one kernel ----------------
__global__ __launch_bounds__(256) void setup2_k(const void* __restrict__ X,
                                                const void* __restrict__ Wsh,
                                                const void* __restrict__ W0, const void* __restrict__ W1,
                                                const void* __restrict__ W2, const void* __restrict__ G0,
                                                const void* __restrict__ G1, const void* __restrict__ G2,
                                                const void* __restrict__ linW, const void* __restrict__ linb,
                                                const int* __restrict__ rows, const int* __restrict__ cols,
                                                const void* __restrict__ vals,
                                                const int* __restrict__ rp, const int* __restrict__ cp,
                                                int* __restrict__ rfill, int* __restrict__ cfill,
                                                int2* __restrict__ rpack, int2* __restrict__ cpack,
                                                u16* __restrict__ Xb, u16* __restrict__ WshT,
                                                u16* __restrict__ WTb, u16* __restrict__ WgTb,
                                                float* __restrict__ linWf, float* __restrict__ linbf,
                                                const int* __restrict__ flag) {
  int fl = *flag;
  int bx = blockIdx.x;
  if (bx >= 10245) {  // scatter part
    int e = (bx - 10245) * 256 + threadIdx.x;
    if (e >= NEd) return;
    float v = fl ? bf2f(((const u16*)vals)[e]) : ((const float*)vals)[e];
    int r = rows[e], c = cols[e];
    int p1 = rp[r] + atomicAdd(&rfill[r], 1);
    rpack[p1] = make_int2(c, __float_as_int(v));
    int p2 = cp[c] + atomicAdd(&cfill[c], 1);
    cpack[p2] = make_int2(r, __float_as_int(v));
    return;
  }
  int i = bx * 256 + threadIdx.x;
  if (i < 2097152) {
    Xb[i] = fl ? ((const u16*)X)[i] : f2bf(((const float*)X)[i]);
    return;
  }
  int i2 = i - 2097152;
  if (i2 < 131072) {
    int r = i2 >> 8, c = i2 & 255;
    u16 v = fl ? ((const u16*)Wsh)[i2] : f2bf(((const float*)Wsh)[i2]);
    WshT[c * 512 + r] = v;
    return;
  }
  int i3 = i2 - 131072;
  if (i3 < 393216) {
    int w = i3 >> 16, j = i3 & 65535;
    int r = j >> 8, c = j & 255;
    const void* src = (w == 0) ? W0 : (w == 1) ? W1 : (w == 2) ? W2
                     : (w == 3) ? G0 : (w == 4) ? G1 : G2;
    u16 v = fl ? ((const u16*)src)[j] : f2bf(((const float*)src)[j]);
    u16* dst = (w < 3) ? (WTb + w * 65536) : (WgTb + (w - 3) * 65536);
    dst[c * 256 + r] = v;
    return;
  }
  int i4 = i3 - 393216;
  if (i4 < 1024) { linWf[i4] = fl ? bf2f(((const u16*)linW)[i4]) : ((const float*)linW)[i4]; return; }
  if (i4 < 1026) { int k = i4 - 1024; linbf[k] = fl ? bf2f(((const u16*)linb)[k]) : ((const float*)linb)[k]; }
}

// ---------------- batched SpMM (CSR, int2 edges, bf16 gather, f32 accum) --------
// edge loop unrolled x2: both edges' loads issued before the ordered FMAs
// (nested fmaf keeps exact sequential summation order -> bit-identical).
struct SPP {
  const int* ptr; const int2* ep;
  const u16* m[3]; u16* ob[3]; unsigned long long oo[3];
};
__global__ __launch_bounds__(256) void spmm_mb_k(SPP s, int mode,
                                                 const int* __restrict__ flag) {
  const int b = blockIdx.y;
  int gid = blockIdx.x * 256 + threadIdx.x;
  int row = gid >> 6, lane = gid & 63, f = lane << 2;
  int beg = s.ptr[row], end = s.ptr[row + 1];
  const u16* m = s.m[b];
  float ax = 0.f, ay = 0.f, az = 0.f, aw = 0.f;
  int e = beg;
  for (; e + 1 < end; e += 2) {
    int2 c0 = s.ep[e];
    int2 c1 = s.ep[e + 1];
    ushort4 m0 = *(const ushort4*)(m + (size_t)c0.x * HIDd + f);
    ushort4 m1 = *(const ushort4*)(m + (size_t)c1.x * HIDd + f);
    float v0 = __int_as_float(c0.y), v1 = __int_as_float(c1.y);
    ax = fmaf(v1, bf2f(m1.x), fmaf(v0, bf2f(m0.x), ax));
    ay = fmaf(v1, bf2f(m1.y), fmaf(v0, bf2f(m0.y), ay));
    az = fmaf(v1, bf2f(m1.z), fmaf(v0, bf2f(m0.z), az));
    aw = fmaf(v1, bf2f(m1.w), fmaf(v0, bf2f(m0.w), aw));
  }
  if (e < end) {
    int2 cv = s.ep[e];
    float v = __int_as_float(cv.y);
    ushort4 mv = *(const ushort4*)(m + (size_t)cv.x * HIDd + f);
    ax = fmaf(v, bf2f(mv.x), ax);
    ay = fmaf(v, bf2f(mv.y), ay);
    az = fmaf(v, bf2f(mv.z), az);
    aw = fmaf(v, bf2f(mv.w), aw);
  }
  size_t o = (size_t)row * HIDd + f;
  if (mode == 0) {
    ax = fmaxf(ax, 0.f); ay = fmaxf(ay, 0.f);
    az = fmaxf(az, 0.f); aw = fmaxf(aw, 0.f);
  }
  ushort4 o4 = { f2bf(ax), f2bf(ay), f2bf(az), f2bf(aw) };
  *(ushort4*)(s.ob[b] + o) = o4;
  (void)flag;
}

// ---------------- combine: z_b = relu(g_b + sum4 partials) -> zbb + d_out ------
struct CMB { const float* gt[3]; u16* ob[3]; unsigned long long oo[3]; };
__global__ __launch_bounds__(256) void combine_k(CMB c, const float* __restrict__ part,
                                                 void* __restrict__ outbase,
                                                 const int* __restrict__ flag) {
  const int b = blockIdx.y;
  size_t o = ((size_t)blockIdx.x * 256 + threadIdx.x) * 4;
  const float* pb = part + (size_t)b * 1048576 + o;
  float4 g  = *(const float4*)(c.gt[b] + o);
  float4 p0 = *(const float4*)(pb);
  float4 p1 = *(const float4*)(pb + 3145728);
  float4 p2 = *(const float4*)(pb + 2 * 3145728);
  float4 p3 = *(const float4*)(pb + 3 * 3145728);
  // same order as before: gather-acc + (p0+p1+p2+p3), left-assoc partial sum
  float ax = g.x + (p0.x + p1.x + p2.x + p3.x);
  float ay = g.y + (p0.y + p1.y + p2.y + p3.y);
  float az = g.z + (p0.z + p1.z + p2.z + p3.z);
  float aw = g.w + (p0.w + p1.w + p2.w + p3.w);
  ax = fmaxf(ax, 0.f); ay = fmaxf(ay, 0.f);
  az = fmaxf(az, 0.f); aw = fmaxf(aw, 0.f);
  ushort4 o4 = { f2bf(ax), f2bf(ay), f2bf(az), f2bf(aw) };
  *(ushort4*)(c.ob[b] + o) = o4;
  if (*flag) *(ushort4*)((u16*)outbase + c.oo[b] + o) = o4;
  else       *(float4*)((float*)outbase + c.oo[b] + o) = make_float4(ax, ay, az, aw);
}

// ---------------- redt only (tT partial reduce) ----------------
__global__ __launch_bounds__(256) void redt_k(const float* __restrict__ part,
                                              u16* __restrict__ tT) {
  int i = (blockIdx.x * 256 + threadIdx.x) * 4;
  float4 s0 = *(const float4*)(part + i);
  float4 s1 = *(const float4*)(part + i + 3145728);
  float4 s2 = *(const float4*)(part + i + 2 * 3145728);
  float4 s3 = *(const float4*)(part + i + 3 * 3145728);
  ushort4 o = { f2bf(s0.x + s1.x + s2.x + s3.x), f2bf(s0.y + s1.y + s2.y + s3.y),
                f2bf(s0.z + s1.z + s2.z + s3.z), f2bf(s0.w + s1.w + s2.w + s3.w) };
  *(ushort4*)(tT + i) = o;
}

// ---------------- tall-tile split-K GEMM + optional fused gather ------
// blockIdx.x <  128 : tall GEMM (J4/J5 structure, unchanged arithmetic)
// blockIdx.x >= 128 : gather blocks (512 thr = 8 rows).
//   gmode 0: CSC spmm-u -> bf16 ub   (J4 launch: u_b = A^T @ hp_b)
//   gmode 1: CSR A@u    -> f32  gf   (J5 launch: g_b = A @ u_b)
// Gathers depend only on data ready before the dispatch -> overlap MFMA.
struct TQ {
  const u16* Ap[3]; const u16* Bp[3]; unsigned long long c0[3];
  int tallA, K, N, kspan, gmode;
  const int* cp; const int2* cep;
  const u16* hp[3]; u16* ub[3]; float* gf[3];
};

__global__ __launch_bounds__(512) void tall_spmmu_k(TQ P, float* __restrict__ partf) {
  __shared__ __align__(16) u16 smem[24576];   // 48 KB
  const int b = blockIdx.z;
  const int bx = blockIdx.x;
  if (bx >= 128) {
    // ---- fused gather ----
    int gid = (bx - 128) * 512 + threadIdx.x;
    int row = gid >> 6, lane = gid & 63, f = lane << 2;
    int beg = P.cp[row], end = P.cp[row + 1];
    const u16* m = P.hp[b];
    float ax = 0.f, ay = 0.f, az = 0.f, aw = 0.f;
    int e = beg;
    for (; e + 1 < end; e += 2) {
      int2 c0 = P.cep[e];
      int2 c1 = P.cep[e + 1];
      ushort4 m0 = *(const ushort4*)(m + (size_t)c0.x * HIDd + f);
      ushort4 m1 = *(const ushort4*)(m + (size_t)c1.x * HIDd + f);
      float v0 = __int_as_float(c0.y), v1 = __int_as_float(c1.y);
      ax = fmaf(v1, bf2f(m1.x), fmaf(v0, bf2f(m0.x), ax));
      ay = fmaf(v1, bf2f(m1.y), fmaf(v0, bf2f(m0.y), ay));
      az = fmaf(v1, bf2f(m1.z), fmaf(v0, bf2f(m0.z), az));
      aw = fmaf(v1, bf2f(m1.w), fmaf(v0, bf2f(m0.w), aw));
    }
    if (e < end) {
      int2 cv = P.cep[e];
      float v = __int_as_float(cv.y);
      ushort4 mv = *(const ushort4*)(m + (size_t)cv.x * HIDd + f);
      ax = fmaf(v, bf2f(mv.x), ax);
      ay = fmaf(v, bf2f(mv.y), ay);
      az = fmaf(v, bf2f(mv.z), az);
      aw = fmaf(v, bf2f(mv.w), aw);
    }
    size_t o = (size_t)row * HIDd + f;
    if (P.gmode) {
      *(float4*)(P.gf[b] + o) = make_float4(ax, ay, az, aw);
    } else {
      ushort4 o4 = { f2bf(ax), f2bf(ay), f2bf(az), f2bf(aw) };
      *(ushort4*)(P.ub[b] + o) = o4;
    }
    return;
  }
  // ---- tall GEMM ----
  const u16* A = P.Ap[b];
  const u16* B = P.Bp[b];
  const int K = P.K, N = P.N, tallA = P.tallA;
  const int stripe = bx & 31, ks = bx >> 5;
  const int tid = threadIdx.x, w = tid >> 6, lane = tid & 63;
  const int lr = lane >> 3, cc = lane & 7;
  const int scol = (cc ^ lr) << 3;
  u16* As = smem;
  u16* Bs = smem + (tallA ? 16384 : 8192);
  int wrow, wcol;
  if (tallA) { wrow = (w >> 1) * 64; wcol = (w & 1) * 64; }
  else       { wrow = (w >> 2) * 64; wcol = (w & 3) * 64; }
  const int row0 = tallA ? 0 : stripe * 128;
  const int col0 = tallA ? stripe * 128 : 0;
  const int na = tallA ? 4 : 2;   // A chunks (1 KB) per wave
  const int nb = tallA ? 2 : 4;   // B chunks per wave
  floatx4 acc[4][4] = {};
  int aoff[4], boff[4];
#pragma unroll
  for (int i = 0; i < 4; ++i) {
    int m = wrow + i * 16 + (lane & 15);        // local A row
    aoff[i] = m * 64 + (((lane >> 4) << 3) ^ ((m & 7) << 3));
    int n = wcol + i * 16 + (lane & 15);        // local B row
    boff[i] = n * 64 + (((lane >> 4) << 3) ^ ((n & 7) << 3));
  }
  const int kbeg = ks * P.kspan, kend = kbeg + P.kspan;
  for (int k0 = kbeg; k0 < kend; k0 += 64) {
#pragma unroll
    for (int t = 0; t < 4; ++t) {
      if (t < na) {
        int ch = na * w + t;
        GLDS(A + (size_t)(row0 + 8 * ch + lr) * K + k0 + scol, As + ch * 512);
      }
      if (t < nb) {
        int ch = nb * w + t;
        GLDS(B + (size_t)(col0 + 8 * ch + lr) * K + k0 + scol, Bs + ch * 512);
      }
    }
    __syncthreads();
#pragma unroll
    for (int kk = 0; kk < 2; ++kk) {
      bf16x8 af[4], bfr[4];
#pragma unroll
      for (int i = 0; i < 4; ++i) {
        af[i]  = *(const bf16x8*)(As + (aoff[i] ^ (kk << 5)));
        bfr[i] = *(const bf16x8*)(Bs + (boff[i] ^ (kk << 5)));
      }
#pragma unroll
      for (int i = 0; i < 4; ++i)
#pragma unroll
        for (int j = 0; j < 4; ++j)
          acc[i][j] = __builtin_amdgcn_mfma_f32_16x16x32_bf16(af[i], bfr[j], acc[i][j], 0, 0, 0);
    }
    __syncthreads();
  }
  const int l15 = lane & 15, q4 = (lane >> 4) << 2;
  float* C = partf + P.c0[b] + (size_t)ks * 3145728;
  const int cbase = col0 + wcol + l15;
#pragma unroll
  for (int i = 0; i < 4; ++i)
#pragma unroll
    for (int r = 0; r < 4; ++r) {
      size_t rb = (size_t)(row0 + wrow + i * 16 + q4 + r) * N + cbase;
#pragma unroll
      for (int j = 0; j < 4; ++j) C[rb + j * 16] = acc[i][j][r];
    }
}

// ---------------- job-table bf16 MFMA NT GEMM ----------------
// modes: 0 bf16->ws; 1 sigmoid->bf16 d_out; 3 adaptive d_out; 4 dual bf16->ws;
//        6 head (log_softmax). sym: upper tiles + mirror.
struct Job {
  const u16* A; const u16* B;
  const float* F1; const float* F2;
  unsigned long long c0, c1, pstride;
  int M, N, K, mode, xt, ntiles, nks, kspan, sym;
};
struct Jobs { Job j[6]; };

__global__ __launch_bounds__(256) void gemm_mega(Jobs P, void* __restrict__ WSv,
                                                 void* __restrict__ OutO,
                                                 const int* __restrict__ flag) {
  __shared__ __align__(16) u16 smem[17408];
  u16* As = smem;
  u16* Bs = smem + 8192;
  u16* Ts = smem;
  const Job jb = P.j[blockIdx.z];
  const unsigned tile = blockIdx.x;
  if ((int)tile >= jb.ntiles * jb.nks) return;
  if (jb.mode == 6) {  // head: pred_T = log_softmax([ziv|zc] @ lw + lb)
    int i = tile * 256 + threadIdx.x;
    const float* lw = jb.F1;
    float a0 = jb.F2[0], a1 = jb.F2[1];
    for (int f = 0; f < HIDd; ++f) {
      float zv = bf2f(jb.A[(size_t)i * HIDd + f]);
      a0 = fmaf(zv, lw[2 * f + 0], a0);
      a1 = fmaf(zv, lw[2 * f + 1], a1);
    }
    for (int f = 0; f < HIDd; ++f) {
      float zv = bf2f(jb.B[(size_t)i * HIDd + f]);
      a0 = fmaf(zv, lw[2 * (HIDd + f) + 0], a0);
      a1 = fmaf(zv, lw[2 * (HIDd + f) + 1], a1);
    }
    float mx = fmaxf(a0, a1);
    float lse = mx + logf(expf(a0 - mx) + expf(a1 - mx));
    float p0 = a0 - lse, p1 = a1 - lse;
    if (*flag) {
      u16* ob = (u16*)OutO;
      ob[jb.c0 + 2 * i + 0] = f2bf(p0);
      ob[jb.c0 + 2 * i + 1] = f2bf(p1);
      if (i == 0) ob[jb.c1] = 0;
    } else {
      float* ob = (float*)OutO;
      ob[jb.c0 + 2 * i + 0] = p0;
      ob[jb.c0 + 2 * i + 1] = p1;
      if (i == 0) ob[jb.c1] = 0.f;
    }
    return;
  }
  const unsigned ks = tile / (unsigned)jb.ntiles;
  const unsigned t2 = tile - ks * jb.ntiles;
  unsigned ty, tx;
  if (jb.sym) {
    unsigned rem = t2, rowlen = jb.xt; ty = 0;
    while (rem >= rowlen) { rem -= rowlen; --rowlen; ++ty; }
    tx = ty + rem;
  } else {
    ty = t2 / (unsigned)jb.xt;
    tx = t2 - ty * jb.xt;
  }
  const int K = jb.K, N = jb.N;
  const int row0 = ty * 128, col0 = tx * 128;
  const int tid = threadIdx.x;
  const int w = tid >> 6, lane = tid & 63;
  const int wr = (w >> 1) * 64, wc = (w & 1) * 64;
  const int lr = lane >> 3, cc = lane & 7;
  const int scol = (cc ^ lr) << 3;
  floatx4 acc[4][4] = {};
  int aoff[4], boff[4];
#pragma unroll
  for (int i = 0; i < 4; ++i) {
    int m = wr + i * 16 + (lane & 15);
    aoff[i] = m * 64 + ((((lane >> 4) << 3)) ^ ((m & 7) << 3));
    int n = wc + i * 16 + (lane & 15);
    boff[i] = n * 64 + ((((lane >> 4) << 3)) ^ ((n & 7) << 3));
  }
  const u16* A = jb.A;
  const u16* B = jb.B;
  const int kbeg = ks * jb.kspan, kend = kbeg + jb.kspan;
  for (int k0 = kbeg; k0 < kend; k0 += 64) {
#pragma unroll
    for (int t = 0; t < 4; ++t) {
      int ch = 4 * w + t;
      GLDS(A + (size_t)(row0 + 8 * ch + lr) * K + k0 + scol, As + ch * 512);
      GLDS(B + (size_t)(col0 + 8 * ch + lr) * K + k0 + scol, Bs + ch * 512);
    }
    __syncthreads();
#pragma unroll
    for (int kk = 0; kk < 2; ++kk) {
      bf16x8 af[4], bfr[4];
#pragma unroll
      for (int i = 0; i < 4; ++i) {
        af[i]  = *(const bf16x8*)(As + (aoff[i] ^ (kk << 5)));
        bfr[i] = *(const bf16x8*)(Bs + (boff[i] ^ (kk << 5)));
      }
#pragma unroll
      for (int i = 0; i < 4; ++i)
#pragma unroll
        for (int j = 0; j < 4; ++j)
          acc[i][j] = __builtin_amdgcn_mfma_f32_16x16x32_bf16(af[i], bfr[j], acc[i][j], 0, 0, 0);
    }
    __syncthreads();
  }

  const int l15 = lane & 15, q4 = (lane >> 4) << 2;
  const int cb = col0 + wc + l15;
  const int mode = jb.mode;
  if (mode == 0 || mode == 1) {
    u16* C = ((mode == 1) ? (u16*)OutO : (u16*)WSv) + jb.c0;
#pragma unroll
    for (int i = 0; i < 4; ++i)
#pragma unroll
      for (int r = 0; r < 4; ++r) {
        int lrow = wr + i * 16 + q4 + r;
        size_t rb = (size_t)(row0 + lrow) * N + cb;
#pragma unroll
        for (int j = 0; j < 4; ++j) {
          float v = acc[i][j][r];
          if (mode == 1) v = 1.f / (1.f + __expf(-v));
          u16 vb = f2bf(v);
          C[rb + j * 16] = vb;
          if (jb.sym) Ts[(wc + j * 16 + l15) * 136 + lrow] = vb;
        }
      }
    if (jb.sym && tx != ty) {
      __syncthreads();
      int rr = tid >> 1, hf = (tid & 1) << 6;
      size_t rb2 = (size_t)(col0 + rr) * N + row0 + hf;
#pragma unroll
      for (int k = 0; k < 8; ++k)
        *(uint4*)(C + rb2 + k * 8) = *(const uint4*)(Ts + rr * 136 + hf + k * 8);
    }
  } else if (mode == 4) {
    u16* C  = (u16*)WSv + jb.c0;
    u16* CT = (u16*)WSv + jb.c1;
    const int M = jb.M;
#pragma unroll
    for (int i = 0; i < 4; ++i)
#pragma unroll
      for (int r = 0; r < 4; ++r) {
        int gr = row0 + wr + i * 16 + q4 + r;
#pragma unroll
        for (int j = 0; j < 4; ++j) {
          u16 v = f2bf(acc[i][j][r]);
          int gc = cb + j * 16;
          C[(size_t)gr * N + gc] = v;
          CT[(size_t)gc * M + gr] = v;
        }
      }
  } else {  // mode 3: adaptive dtype store into d_out
    if (*flag) {
      u16* C = (u16*)OutO + jb.c0;
#pragma unroll
      for (int i = 0; i < 4; ++i)
#pragma unroll
        for (int r = 0; r < 4; ++r) {
          int lrow = wr + i * 16 + q4 + r;
          size_t rb = (size_t)(row0 + lrow) * N + cb;
#pragma unroll
          for (int j = 0; j < 4; ++j) {
            u16 vb = f2bf(acc[i][j][r]);
            C[rb + j * 16] = vb;
            if (jb.sym) Ts[(wc + j * 16 + l15) * 136 + lrow] = vb;
          }
        }
      if (jb.sym && tx != ty) {
        __syncthreads();
        int rr = tid >> 1, hf = (tid & 1) << 6;
        size_t rb2 = (size_t)(col0 + rr) * N + row0 + hf;
#pragma unroll
        for (int k = 0; k < 8; ++k)
          *(uint4*)(C + rb2 + k * 8) = *(const uint4*)(Ts + rr * 136 + hf + k * 8);
      }
    } else {
      float* C = (float*)OutO + jb.c0;
      // direct (upper-triangle) tile: coalesced 64B quarter-wave stores
#pragma unroll
      for (int i = 0; i < 4; ++i)
#pragma unroll
        for (int r = 0; r < 4; ++r) {
          int gr = row0 + wr + i * 16 + q4 + r;
          size_t rb = (size_t)gr * N + cb;
#pragma unroll
          for (int j = 0; j < 4; ++j) C[rb + j * 16] = acc[i][j][r];
        }
      // mirror tile: LDS-staged f32 transpose in two 64-column half-passes,
      // then fully-coalesced 128-float row writes.
      if (jb.sym && tx != ty) {
        float* Tf = (float*)smem;          // 64 x 132 f32 = 33792 B <= 34816 B
        const int whalf = w & 1;           // wave's column half (wc = whalf*64)
#pragma unroll
        for (int half = 0; half < 2; ++half) {
          __syncthreads();                  // smem (As/Bs or prev half) dead
          if (whalf == half) {
#pragma unroll
            for (int i = 0; i < 4; ++i)
#pragma unroll
              for (int j = 0; j < 4; ++j) {
                int cl = j * 16 + l15;      // column-local within this half
#pragma unroll
                for (int r = 0; r < 4; ++r)
                  Tf[cl * 132 + wr + i * 16 + q4 + r] = acc[i][j][r];
              }
          }
          __syncthreads();
          int cl = tid >> 2, chf = (tid & 3) << 5;   // 4 threads per row, 32 f ea
          size_t rb2 = (size_t)(col0 + half * 64 + cl) * N + row0 + chf;
          const float* src = Tf + cl * 132 + chf;
#pragma unroll
          for (int k = 0; k < 8; ++k)
            *(float4*)(C + rb2 + k * 4) = *(const float4*)(src + k * 4);
        }
      }
    }
  }
}

// =======================================================================
extern "C" void kernel_launch(void* const* d_in, const int* in_sizes, int n_in,
                              void* d_out, int out_size, void* d_ws, size_t ws_size,
                              hipStream_t stream) {
  const void* X    = d_in[0];
  const int*  rows = (const int*)d_in[1];
  const int*  cols = (const int*)d_in[2];
  const void* vals = d_in[3];
  const void* Wsh  = d_in[4];

  char* W = (char*)d_ws;
  u16*  Xb    = (u16*)(W + 0);
  u16*  WshT  = (u16*)(W + 4194304);
  u16*  WTb   = (u16*)(W + 4456448);
  u16*  WgTb  = (u16*)(W + 4849664);
  int*  rp    = (int*)(W + 5242880);
  int*  cp    = (int*)(W + 5275648);
  int*  rfill = (int*)(W + 5308416);
  int*  cfill = (int*)(W + 5324800);
  int2* rpack = (int2*)(W + 5341184);   // 1 MB
  int2* cpack = (int2*)(W + 6389760);   // 1 MB
  float* linWf = (float*)(W + 7438336);
  float* linbf = (float*)(W + 7442432);
  int*  flag  = (int*)(W + 7442560);
  u16*  hb    = (u16*)(W + 8388608);
  u16*  tmpb[3] = { (u16*)(W + 10485760), (u16*)(W + 12582912), (u16*)(W + 14680064) };
  u16*  z0b[3]  = { (u16*)(W + 16777216), (u16*)(W + 18874368), (u16*)(W + 20971520) };
  u16*  hpb[3]  = { (u16*)(W + 23068672), (u16*)(W + 25165824), (u16*)(W + 27262976) };
  u16*  hpT[3]  = { (u16*)(W + 29360128), (u16*)(W + 31457280), (u16*)(W + 33554432) };
  u16*  tTb     = (u16*)(W + 35651584);
  u16*  zbb[3]  = { (u16*)(W + 41943040), (u16*)(W + 44040192), (u16*)(W + 46137344) };
  u16*  ubb[3]  = { (u16*)(W + 48234496), (u16*)(W + 50331648), (u16*)(W + 52428800) };
  float* partf  = (float*)(W + 54525952);   // 48 MB split-K partials (also hist slabs)
  int*  slabs  = (int*)(W + 54525952);      // 1 MB, consumed before partials
  // g_b = A @ u_b f32 temps (4 MB each), in regions dead by step 11:
  //   Xb (dead after J1), tmpb (dead after step 7), z0b (dead after J3)
  float* gtmp[3] = { (float*)(W + 0), (float*)(W + 10485760), (float*)(W + 16777216) };

  const long long z_off[3]   = { 0LL, 17825792LL, 35651584LL };
  const long long rec_off[3] = { 1048576LL, 18874368LL, 36700160LL };
  const long long mi_off = 53477376LL, pred_off = 53477377LL;

  const u16* r2p[3] = { (const u16*)d_out + rec_off[0], (const u16*)d_out + rec_off[1],
                        (const u16*)d_out + rec_off[2] };

  // 1. private-LDS histograms -> slabs
  hist_priv_k<<<32, 256, 0, stream>>>(rows, cols, slabs);
  // 2. scan + dtype detect + zero fills
  scan2_k<<<1, 1024, 0, stream>>>((const unsigned int*)X, slabs, rp, cp, rfill, cfill, flag);
  // 3. converts/transposes + scatter
  setup2_k<<<10757, 256, 0, stream>>>(X, Wsh, d_in[5], d_in[6], d_in[7],
                                      d_in[8], d_in[9], d_in[10], d_in[11], d_in[12],
                                      rows, cols, vals, rp, cp, rfill, cfill, rpack, cpack,
                                      Xb, WshT, WTb, WgTb, linWf, linbf, flag);

  Jobs P{};
  auto setj = [](Job& j, const u16* A, const u16* B, unsigned long long c0,
                 unsigned long long c1, unsigned long long ps, int M, int N, int K,
                 int mode, int nks, int sym) {
    j.A = A; j.B = B; j.F1 = nullptr; j.F2 = nullptr;
    j.c0 = c0; j.c1 = c1; j.pstride = ps;
    j.M = M; j.N = N; j.K = K; j.mode = mode;
    j.xt = N / 128;
    j.ntiles = sym ? (j.xt * (j.xt + 1)) / 2 : (M / 128) * (N / 128);
    j.nks = nks; j.kspan = K / nks; j.sym = sym;
  };

  // 4. J1: tmp0 = X @ Wsh
  setj(P.j[0], Xb, WshT, ((char*)tmpb[0] - W) / 2, 0, 0, Nn, HIDd, FINd, 0, 1, 0);
  gemm_mega<<<dim3(64, 1, 1), 256, 0, stream>>>(P, d_ws, d_out, flag);

  // 5. h = relu(A @ tmp0)
  SPP s{};
  s.ptr = rp; s.ep = rpack;
  s.m[0] = tmpb[0]; s.ob[0] = hb;
  spmm_mb_k<<<dim3(Nn / 4, 1), 256, 0, stream>>>(s, 0, flag);

  // 6. J2: tmp_b = h @ W_b
  for (int b = 0; b < 3; ++b)
    setj(P.j[b], hb, WTb + b * 65536, ((char*)tmpb[b] - W) / 2, 0, 0, Nn, HIDd, HIDd, 0, 1, 0);
  gemm_mega<<<dim3(64, 1, 3), 256, 0, stream>>>(P, d_ws, d_out, flag);

  // 7. z0_b = relu(A @ tmp_b)
  for (int b = 0; b < 3; ++b) { s.m[b] = tmpb[b]; s.ob[b] = z0b[b]; }
  spmm_mb_k<<<dim3(Nn / 4, 3), 256, 0, stream>>>(s, 0, flag);

  // 8. J3: r2_b = sigmoid(z0 z0^T) [SYM] + hp_b = z0 @ Wg_b [dual]
  for (int b = 0; b < 3; ++b) {
    setj(P.j[b], z0b[b], z0b[b], rec_off[b], 0, 0, Nn, Nn, HIDd, 1, 1, 1);
    setj(P.j[3 + b], z0b[b], WgTb + b * 65536, ((char*)hpb[b] - W) / 2,
         ((char*)hpT[b] - W) / 2, 0, Nn, HIDd, HIDd, 4, 1, 0);
  }
  gemm_mega<<<dim3(528, 1, 6), 256, 0, stream>>>(P, d_ws, d_out, flag);

  // 9. J4 (tall-A) + fused spmm-u: tT partials = h'^T @ r2 (128 blocks)
  //    + u_b = A^T @ hp_b (512 CSC gather blocks, overlap MFMA)
  TQ T{};
  for (int b = 0; b < 3; ++b) {
    T.Ap[b] = hpT[b]; T.Bp[b] = r2p[b];
    T.c0[b] = (unsigned long long)b * 1048576ULL;
    T.hp[b] = hpb[b]; T.ub[b] = ubb[b]; T.gf[b] = nullptr;
  }
  T.tallA = 1; T.K = Nn; T.N = Nn; T.kspan = 1024; T.gmode = 0;
  T.cp = cp; T.cep = cpack;
  tall_spmmu_k<<<dim3(640, 1, 3), 512, 0, stream>>>(T, partf);

  // 10. redt (tT partials -> bf16)
  redt_k<<<3072, 256, 0, stream>>>(partf, tTb);

  // 11. J5 (tall-B) + fused A@u: buf partials = r2 @ t (128 blocks)
  //     + g_b = A @ u_b (512 CSR gather blocks -> f32 gtmp, overlap MFMA)
  TQ T2{};
  for (int b = 0; b < 3; ++b) {
    T2.Ap[b] = r2p[b]; T2.Bp[b] = tTb + b * 1048576;
    T2.c0[b] = (unsigned long long)b * 1048576ULL;
    T2.hp[b] = ubb[b]; T2.ub[b] = nullptr; T2.gf[b] = gtmp[b];
  }
  T2.tallA = 0; T2.K = Nn; T2.N = HIDd; T2.kspan = 1024; T2.gmode = 1;
  T2.cp = rp; T2.cep = rpack;
  tall_spmmu_k<<<dim3(640, 1, 3), 512, 0, stream>>>(T2, partf);

  // 12. combine: z_b = relu(g_b + sum4(buf parts)) -> zbb + d_out
  CMB cmb{};
  for (int b = 0; b < 3; ++b) {
    cmb.gt[b] = gtmp[b];
    cmb.ob[b] = zbb[b]; cmb.oo[b] = (unsigned long long)z_off[b];
  }
  combine_k<<<dim3(1024, 3), 256, 0, stream>>>(cmb, partf, d_out, flag);

  // 13. J6: zrec_b = z z^T -> d_out [SYM, adaptive] + head [mode 6]
  for (int b = 0; b < 3; ++b)
    setj(P.j[b], zbb[b], zbb[b], rec_off[b], 0, 0, Nn, Nn, HIDd, 3, 1, 1);
  setj(P.j[3], zbb[0], zbb[1], (unsigned long long)pred_off,
       (unsigned long long)mi_off, 0, 256, 128, 64, 6, 1, 0);
  P.j[3].ntiles = 16; P.j[3].nks = 1;
  P.j[3].F1 = linWf; P.j[3].F2 = linbf;
  gemm_mega<<<dim3(528, 1, 4), 256, 0, stream>>>(P, d_ws, d_out, flag);

  (void)in_sizes; (void)n_in; (void)out_size; (void)ws_size;
}

// Round 7
// 624.433 us; speedup vs baseline: 1.0829x; 1.0829x over previous
//
#include <hip/hip_runtime.h>

#define Nn   4096
#define FINd 512
#define HIDd 256
#define NEd  131072

typedef unsigned short u16;
typedef __bf16 bf16x8 __attribute__((ext_vector_type(8)));
typedef float floatx4 __attribute__((ext_vector_type(4)));

// ---------------- bf16 helpers ----------------
__device__ __forceinline__ float bf2f(u16 u) {
  union { unsigned int i; float f; } v; v.i = ((unsigned int)u) << 16; return v.f;
}
__device__ __forceinline__ u16 f2bf(float f) {
  union { unsigned int i; float f; } v; v.f = f;
  unsigned int x = v.i;
  return (u16)((x + 0x7FFFu + ((x >> 16) & 1u)) >> 16);  // RNE
}

#define GLDS(gp, lp) __builtin_amdgcn_global_load_lds( \
    (__attribute__((address_space(1))) unsigned int*)(void*)(gp), \
    (__attribute__((address_space(3))) unsigned int*)(lp), 16, 0, 0)

// 4-edge gather step, order-preserving (sequential fmaf nesting)
#define GATH4(EP, M, F, AX, AY, AZ, AW, E)                                     \
  {                                                                            \
    int2 c0 = (EP)[E]; int2 c1 = (EP)[(E) + 1];                                \
    int2 c2 = (EP)[(E) + 2]; int2 c3 = (EP)[(E) + 3];                          \
    ushort4 m0 = *(const ushort4*)((M) + (size_t)c0.x * HIDd + (F));           \
    ushort4 m1 = *(const ushort4*)((M) + (size_t)c1.x * HIDd + (F));           \
    ushort4 m2 = *(const ushort4*)((M) + (size_t)c2.x * HIDd + (F));           \
    ushort4 m3 = *(const ushort4*)((M) + (size_t)c3.x * HIDd + (F));           \
    float v0 = __int_as_float(c0.y), v1 = __int_as_float(c1.y);                \
    float v2 = __int_as_float(c2.y), v3 = __int_as_float(c3.y);                \
    AX = fmaf(v3, bf2f(m3.x), fmaf(v2, bf2f(m2.x), fmaf(v1, bf2f(m1.x), fmaf(v0, bf2f(m0.x), AX)))); \
    AY = fmaf(v3, bf2f(m3.y), fmaf(v2, bf2f(m2.y), fmaf(v1, bf2f(m1.y), fmaf(v0, bf2f(m0.y), AY)))); \
    AZ = fmaf(v3, bf2f(m3.z), fmaf(v2, bf2f(m2.z), fmaf(v1, bf2f(m1.z), fmaf(v0, bf2f(m0.z), AZ)))); \
    AW = fmaf(v3, bf2f(m3.w), fmaf(v2, bf2f(m2.w), fmaf(v1, bf2f(m1.w), fmaf(v0, bf2f(m0.w), AW)))); \
  }

// ---------------- private-LDS histogram -> slabs (no global atomics) ----------
__global__ __launch_bounds__(256) void hist_priv_k(const int* __restrict__ rows,
                                                   const int* __restrict__ cols,
                                                   int* __restrict__ slabs) {
  __shared__ int cnt[8192];
  const int t = threadIdx.x;
  for (int i = t; i < 8192; i += 256) cnt[i] = 0;
  __syncthreads();
  int base = blockIdx.x * 4096;
  for (int i = t; i < 4096; i += 256) {
    int e = base + i;
    atomicAdd(&cnt[rows[e]], 1);
    atomicAdd(&cnt[4096 + cols[e]], 1);
  }
  __syncthreads();
  int* out = slabs + blockIdx.x * 8192;
  for (int i = t; i < 8192; i += 256) out[i] = cnt[i];
}

// ---------------- scan (sum 32 slabs -> rp/cp) + dtype detect + zero fills ------
__global__ __launch_bounds__(1024) void scan2_k(const unsigned int* __restrict__ X,
                                                const int* __restrict__ slabs,
                                                int* __restrict__ rp, int* __restrict__ cp,
                                                int* __restrict__ rfill, int* __restrict__ cfill,
                                                int* __restrict__ flag) {
  __shared__ int part[1024];
  __shared__ int dcnt;
  const int t = threadIdx.x;
  if (t == 0) dcnt = 0;
  __syncthreads();
  int local = 0;
  for (int i = t; i < 4096; i += 1024) {
    unsigned e = (X[i] >> 7) & 0xFFu;
    if (e >= 100u && e <= 140u) local++;
  }
  if (local) atomicAdd(&dcnt, local);
  int base = t * 8, s = 0, loc[8];
  int csum[8];
#pragma unroll
  for (int j = 0; j < 8; ++j) csum[j] = 0;
  for (int sl = 0; sl < 32; ++sl) {
    const int* sp = slabs + sl * 8192 + base;
#pragma unroll
    for (int j = 0; j < 8; ++j) csum[j] += sp[j];
  }
#pragma unroll
  for (int j = 0; j < 8; ++j) { loc[j] = s; s += csum[j]; }
  part[t] = s;
  __syncthreads();
  if (t == 0) *flag = (dcnt > 2458) ? 1 : 0;
  for (int off = 1; off < 1024; off <<= 1) {
    int v = (t >= off) ? part[t - off] : 0;
    __syncthreads();
    part[t] += v;
    __syncthreads();
  }
  int excl = (t == 0) ? 0 : part[t - 1];
  int rtot = part[511];
  if (t < 512) {
#pragma unroll
    for (int j = 0; j < 8; ++j) rp[base + j] = excl + loc[j];
    if (t == 511) rp[4096] = rtot;
  } else {
    int cb = base - 4096;
    int ex2 = excl - rtot;
#pragma unroll
    for (int j = 0; j < 8; ++j) cp[cb + j] = ex2 + loc[j];
    if (t == 1023) cp[4096] = part[1023] - rtot;
  }
  for (int i = t; i < 4096; i += 1024) { rfill[i] = 0; cfill[i] = 0; }
}

// ---------------- converts/transposes + CSR/CSC scatter, one kernel ----------------
__global__ __launch_bounds__(256) void setup2_k(const void* __restrict__ X,
                                                const void* __restrict__ Wsh,
                                                const void* __restrict__ W0, const void* __restrict__ W1,
                                                const void* __restrict__ W2, const void* __restrict__ G0,
                                                const void* __restrict__ G1, const void* __restrict__ G2,
                                                const void* __restrict__ linW, const void* __restrict__ linb,
                                                const int* __restrict__ rows, const int* __restrict__ cols,
                                                const void* __restrict__ vals,
                                                const int* __restrict__ rp, const int* __restrict__ cp,
                                                int* __restrict__ rfill, int* __restrict__ cfill,
                                                int2* __restrict__ rpack, int2* __restrict__ cpack,
                                                u16* __restrict__ Xb, u16* __restrict__ WshT,
                                                u16* __restrict__ WTb, u16* __restrict__ WgTb,
                                                float* __restrict__ linWf, float* __restrict__ linbf,
                                                const int* __restrict__ flag) {
  int fl = *flag;
  int bx = blockIdx.x;
  if (bx >= 10245) {  // scatter part
    int e = (bx - 10245) * 256 + threadIdx.x;
    if (e >= NEd) return;
    float v = fl ? bf2f(((const u16*)vals)[e]) : ((const float*)vals)[e];
    int r = rows[e], c = cols[e];
    int p1 = rp[r] + atomicAdd(&rfill[r], 1);
    rpack[p1] = make_int2(c, __float_as_int(v));
    int p2 = cp[c] + atomicAdd(&cfill[c], 1);
    cpack[p2] = make_int2(r, __float_as_int(v));
    return;
  }
  int i = bx * 256 + threadIdx.x;
  if (i < 2097152) {
    Xb[i] = fl ? ((const u16*)X)[i] : f2bf(((const float*)X)[i]);
    return;
  }
  int i2 = i - 2097152;
  if (i2 < 131072) {
    int r = i2 >> 8, c = i2 & 255;
    u16 v = fl ? ((const u16*)Wsh)[i2] : f2bf(((const float*)Wsh)[i2]);
    WshT[c * 512 + r] = v;
    return;
  }
  int i3 = i2 - 131072;
  if (i3 < 393216) {
    int w = i3 >> 16, j = i3 & 65535;
    int r = j >> 8, c = j & 255;
    const void* src = (w == 0) ? W0 : (w == 1) ? W1 : (w == 2) ? W2
                     : (w == 3) ? G0 : (w == 4) ? G1 : G2;
    u16 v = fl ? ((const u16*)src)[j] : f2bf(((const float*)src)[j]);
    u16* dst = (w < 3) ? (WTb + w * 65536) : (WgTb + (w - 3) * 65536);
    dst[c * 256 + r] = v;
    return;
  }
  int i4 = i3 - 393216;
  if (i4 < 1024) { linWf[i4] = fl ? bf2f(((const u16*)linW)[i4]) : ((const float*)linW)[i4]; return; }
  if (i4 < 1026) { int k = i4 - 1024; linbf[k] = fl ? bf2f(((const u16*)linb)[k]) : ((const float*)linb)[k]; }
}

// ---------------- batched SpMM (CSR, int2 edges, bf16 gather, f32 accum) --------
// edge loop unrolled x4: four edges' loads issued before the ordered FMAs
// (nested fmaf keeps exact sequential summation order -> bit-identical).
struct SPP {
  const int* ptr; const int2* ep;
  const u16* m[3]; u16* ob[3]; unsigned long long oo[3];
};
__global__ __launch_bounds__(256) void spmm_mb_k(SPP s, const float* __restrict__ part,
                                                 void* __restrict__ outbase, int mode,
                                                 const int* __restrict__ flag) {
  const int b = blockIdx.y;
  int gid = blockIdx.x * 256 + threadIdx.x;
  int row = gid >> 6, lane = gid & 63, f = lane << 2;
  int beg = s.ptr[row], end = s.ptr[row + 1];
  const u16* m = s.m[b];
  float ax = 0.f, ay = 0.f, az = 0.f, aw = 0.f;
  int e = beg;
  for (; e + 3 < end; e += 4) GATH4(s.ep, m, f, ax, ay, az, aw, e);
  for (; e < end; ++e) {
    int2 cv = s.ep[e];
    float v = __int_as_float(cv.y);
    ushort4 mv = *(const ushort4*)(m + (size_t)cv.x * HIDd + f);
    ax = fmaf(v, bf2f(mv.x), ax);
    ay = fmaf(v, bf2f(mv.y), ay);
    az = fmaf(v, bf2f(mv.z), az);
    aw = fmaf(v, bf2f(mv.w), aw);
  }
  size_t o = (size_t)row * HIDd + f;
  if (mode == 2) {
    const float* pb = part + (size_t)b * 1048576 + o;
    float4 p0 = *(const float4*)(pb);
    float4 p1 = *(const float4*)(pb + 3145728);
    float4 p2 = *(const float4*)(pb + 2 * 3145728);
    float4 p3 = *(const float4*)(pb + 3 * 3145728);
    ax += p0.x + p1.x + p2.x + p3.x;
    ay += p0.y + p1.y + p2.y + p3.y;
    az += p0.z + p1.z + p2.z + p3.z;
    aw += p0.w + p1.w + p2.w + p3.w;
    ax = fmaxf(ax, 0.f); ay = fmaxf(ay, 0.f);
    az = fmaxf(az, 0.f); aw = fmaxf(aw, 0.f);
    ushort4 o4 = { f2bf(ax), f2bf(ay), f2bf(az), f2bf(aw) };
    *(ushort4*)(s.ob[b] + o) = o4;
    if (*flag) *(ushort4*)((u16*)outbase + s.oo[b] + o) = o4;
    else       *(float4*)((float*)outbase + s.oo[b] + o) = make_float4(ax, ay, az, aw);
  } else {
    if (mode == 0) {
      ax = fmaxf(ax, 0.f); ay = fmaxf(ay, 0.f);
      az = fmaxf(az, 0.f); aw = fmaxf(aw, 0.f);
    }
    ushort4 o4 = { f2bf(ax), f2bf(ay), f2bf(az), f2bf(aw) };
    *(ushort4*)(s.ob[b] + o) = o4;
  }
}

// ---------------- redt only (tT partial reduce) ----------------
__global__ __launch_bounds__(256) void redt_k(const float* __restrict__ part,
                                              u16* __restrict__ tT) {
  int i = (blockIdx.x * 256 + threadIdx.x) * 4;
  float4 s0 = *(const float4*)(part + i);
  float4 s1 = *(const float4*)(part + i + 3145728);
  float4 s2 = *(const float4*)(part + i + 2 * 3145728);
  float4 s3 = *(const float4*)(part + i + 3 * 3145728);
  ushort4 o = { f2bf(s0.x + s1.x + s2.x + s3.x), f2bf(s0.y + s1.y + s2.y + s3.y),
                f2bf(s0.z + s1.z + s2.z + s3.z), f2bf(s0.w + s1.w + s2.w + s3.w) };
  *(ushort4*)(tT + i) = o;
}

// ---------------- tall-tile split-K GEMM + fused spmm-u (J4) ------
// blockIdx.x <  128 : tall GEMM (J4/J5 structure, unchanged arithmetic)
// blockIdx.x >= 128 : CSC spmm-u gather blocks (512 thr = 8 rows), J4 launch only.
// The gather depends only on hp (ready before this dispatch) -> overlaps MFMA.
struct TQ {
  const u16* Ap[3]; const u16* Bp[3]; unsigned long long c0[3];
  int tallA, K, N, kspan;
  const int* cp; const int2* cep;
  const u16* hp[3]; u16* ub[3];
};

__global__ __launch_bounds__(512) void tall_spmmu_k(TQ P, float* __restrict__ partf) {
  __shared__ __align__(16) u16 smem[24576];   // 48 KB
  const int b = blockIdx.z;
  const int bx = blockIdx.x;
  if (bx >= 128) {
    // ---- fused spmm-u: u_b = A^T @ hp_b (CSC), bf16 store ----
    int gid = (bx - 128) * 512 + threadIdx.x;
    int row = gid >> 6, lane = gid & 63, f = lane << 2;
    int beg = P.cp[row], end = P.cp[row + 1];
    const u16* m = P.hp[b];
    float ax = 0.f, ay = 0.f, az = 0.f, aw = 0.f;
    int e = beg;
    for (; e + 3 < end; e += 4) GATH4(P.cep, m, f, ax, ay, az, aw, e);
    for (; e < end; ++e) {
      int2 cv = P.cep[e];
      float v = __int_as_float(cv.y);
      ushort4 mv = *(const ushort4*)(m + (size_t)cv.x * HIDd + f);
      ax = fmaf(v, bf2f(mv.x), ax);
      ay = fmaf(v, bf2f(mv.y), ay);
      az = fmaf(v, bf2f(mv.z), az);
      aw = fmaf(v, bf2f(mv.w), aw);
    }
    size_t o = (size_t)row * HIDd + f;
    ushort4 o4 = { f2bf(ax), f2bf(ay), f2bf(az), f2bf(aw) };
    *(ushort4*)(P.ub[b] + o) = o4;
    return;
  }
  // ---- tall GEMM ----
  const u16* A = P.Ap[b];
  const u16* B = P.Bp[b];
  const int K = P.K, N = P.N, tallA = P.tallA;
  const int stripe = bx & 31, ks = bx >> 5;
  const int tid = threadIdx.x, w = tid >> 6, lane = tid & 63;
  const int lr = lane >> 3, cc = lane & 7;
  const int scol = (cc ^ lr) << 3;
  u16* As = smem;
  u16* Bs = smem + (tallA ? 16384 : 8192);
  int wrow, wcol;
  if (tallA) { wrow = (w >> 1) * 64; wcol = (w & 1) * 64; }
  else       { wrow = (w >> 2) * 64; wcol = (w & 3) * 64; }
  const int row0 = tallA ? 0 : stripe * 128;
  const int col0 = tallA ? stripe * 128 : 0;
  const int na = tallA ? 4 : 2;   // A chunks (1 KB) per wave
  const int nb = tallA ? 2 : 4;   // B chunks per wave
  floatx4 acc[4][4] = {};
  int aoff[4], boff[4];
#pragma unroll
  for (int i = 0; i < 4; ++i) {
    int m = wrow + i * 16 + (lane & 15);        // local A row
    aoff[i] = m * 64 + (((lane >> 4) << 3) ^ ((m & 7) << 3));
    int n = wcol + i * 16 + (lane & 15);        // local B row
    boff[i] = n * 64 + (((lane >> 4) << 3) ^ ((n & 7) << 3));
  }
  const int kbeg = ks * P.kspan, kend = kbeg + P.kspan;
  for (int k0 = kbeg; k0 < kend; k0 += 64) {
#pragma unroll
    for (int t = 0; t < 4; ++t) {
      if (t < na) {
        int ch = na * w + t;
        GLDS(A + (size_t)(row0 + 8 * ch + lr) * K + k0 + scol, As + ch * 512);
      }
      if (t < nb) {
        int ch = nb * w + t;
        GLDS(B + (size_t)(col0 + 8 * ch + lr) * K + k0 + scol, Bs + ch * 512);
      }
    }
    __syncthreads();
#pragma unroll
    for (int kk = 0; kk < 2; ++kk) {
      bf16x8 af[4], bfr[4];
#pragma unroll
      for (int i = 0; i < 4; ++i) {
        af[i]  = *(const bf16x8*)(As + (aoff[i] ^ (kk << 5)));
        bfr[i] = *(const bf16x8*)(Bs + (boff[i] ^ (kk << 5)));
      }
#pragma unroll
      for (int i = 0; i < 4; ++i)
#pragma unroll
        for (int j = 0; j < 4; ++j)
          acc[i][j] = __builtin_amdgcn_mfma_f32_16x16x32_bf16(af[i], bfr[j], acc[i][j], 0, 0, 0);
    }
    __syncthreads();
  }
  const int l15 = lane & 15, q4 = (lane >> 4) << 2;
  float* C = partf + P.c0[b] + (size_t)ks * 3145728;
  const int cbase = col0 + wcol + l15;
#pragma unroll
  for (int i = 0; i < 4; ++i)
#pragma unroll
    for (int r = 0; r < 4; ++r) {
      size_t rb = (size_t)(row0 + wrow + i * 16 + q4 + r) * N + cbase;
#pragma unroll
      for (int j = 0; j < 4; ++j) C[rb + j * 16] = acc[i][j][r];
    }
}

// ---------------- job-table bf16 MFMA NT GEMM ----------------
// modes: 0 bf16->ws; 1 sigmoid->bf16 d_out; 3 adaptive d_out; 4 dual bf16->ws;
//        6 head (log_softmax). sym: upper tiles + mirror.
struct Job {
  const u16* A; const u16* B;
  const float* F1; const float* F2;
  unsigned long long c0, c1, pstride;
  int M, N, K, mode, xt, ntiles, nks, kspan, sym;
};
struct Jobs { Job j[6]; };

__global__ __launch_bounds__(256) void gemm_mega(Jobs P, void* __restrict__ WSv,
                                                 void* __restrict__ OutO,
                                                 const int* __restrict__ flag) {
  __shared__ __align__(16) u16 smem[17408];
  u16* As = smem;
  u16* Bs = smem + 8192;
  u16* Ts = smem;
  const Job jb = P.j[blockIdx.z];
  const unsigned tile = blockIdx.x;
  if ((int)tile >= jb.ntiles * jb.nks) return;
  if (jb.mode == 6) {  // head: pred_T = log_softmax([ziv|zc] @ lw + lb)
    int i = tile * 256 + threadIdx.x;
    const float* lw = jb.F1;
    float a0 = jb.F2[0], a1 = jb.F2[1];
    for (int f = 0; f < HIDd; ++f) {
      float zv = bf2f(jb.A[(size_t)i * HIDd + f]);
      a0 = fmaf(zv, lw[2 * f + 0], a0);
      a1 = fmaf(zv, lw[2 * f + 1], a1);
    }
    for (int f = 0; f < HIDd; ++f) {
      float zv = bf2f(jb.B[(size_t)i * HIDd + f]);
      a0 = fmaf(zv, lw[2 * (HIDd + f) + 0], a0);
      a1 = fmaf(zv, lw[2 * (HIDd + f) + 1], a1);
    }
    float mx = fmaxf(a0, a1);
    float lse = mx + logf(expf(a0 - mx) + expf(a1 - mx));
    float p0 = a0 - lse, p1 = a1 - lse;
    if (*flag) {
      u16* ob = (u16*)OutO;
      ob[jb.c0 + 2 * i + 0] = f2bf(p0);
      ob[jb.c0 + 2 * i + 1] = f2bf(p1);
      if (i == 0) ob[jb.c1] = 0;
    } else {
      float* ob = (float*)OutO;
      ob[jb.c0 + 2 * i + 0] = p0;
      ob[jb.c0 + 2 * i + 1] = p1;
      if (i == 0) ob[jb.c1] = 0.f;
    }
    return;
  }
  const unsigned ks = tile / (unsigned)jb.ntiles;
  const unsigned t2 = tile - ks * jb.ntiles;
  unsigned ty, tx;
  if (jb.sym) {
    unsigned rem = t2, rowlen = jb.xt; ty = 0;
    while (rem >= rowlen) { rem -= rowlen; --rowlen; ++ty; }
    tx = ty + rem;
  } else {
    ty = t2 / (unsigned)jb.xt;
    tx = t2 - ty * jb.xt;
  }
  const int K = jb.K, N = jb.N;
  const int row0 = ty * 128, col0 = tx * 128;
  const int tid = threadIdx.x;
  const int w = tid >> 6, lane = tid & 63;
  const int wr = (w >> 1) * 64, wc = (w & 1) * 64;
  const int lr = lane >> 3, cc = lane & 7;
  const int scol = (cc ^ lr) << 3;
  floatx4 acc[4][4] = {};
  int aoff[4], boff[4];
#pragma unroll
  for (int i = 0; i < 4; ++i) {
    int m = wr + i * 16 + (lane & 15);
    aoff[i] = m * 64 + ((((lane >> 4) << 3)) ^ ((m & 7) << 3));
    int n = wc + i * 16 + (lane & 15);
    boff[i] = n * 64 + ((((lane >> 4) << 3)) ^ ((n & 7) << 3));
  }
  const u16* A = jb.A;
  const u16* B = jb.B;
  const int kbeg = ks * jb.kspan, kend = kbeg + jb.kspan;
  for (int k0 = kbeg; k0 < kend; k0 += 64) {
#pragma unroll
    for (int t = 0; t < 4; ++t) {
      int ch = 4 * w + t;
      GLDS(A + (size_t)(row0 + 8 * ch + lr) * K + k0 + scol, As + ch * 512);
      GLDS(B + (size_t)(col0 + 8 * ch + lr) * K + k0 + scol, Bs + ch * 512);
    }
    __syncthreads();
#pragma unroll
    for (int kk = 0; kk < 2; ++kk) {
      bf16x8 af[4], bfr[4];
#pragma unroll
      for (int i = 0; i < 4; ++i) {
        af[i]  = *(const bf16x8*)(As + (aoff[i] ^ (kk << 5)));
        bfr[i] = *(const bf16x8*)(Bs + (boff[i] ^ (kk << 5)));
      }
#pragma unroll
      for (int i = 0; i < 4; ++i)
#pragma unroll
        for (int j = 0; j < 4; ++j)
          acc[i][j] = __builtin_amdgcn_mfma_f32_16x16x32_bf16(af[i], bfr[j], acc[i][j], 0, 0, 0);
    }
    __syncthreads();
  }

  const int l15 = lane & 15, q4 = (lane >> 4) << 2;
  const int cb = col0 + wc + l15;
  const int mode = jb.mode;
  if (mode == 0 || mode == 1) {
    u16* C = ((mode == 1) ? (u16*)OutO : (u16*)WSv) + jb.c0;
#pragma unroll
    for (int i = 0; i < 4; ++i)
#pragma unroll
      for (int r = 0; r < 4; ++r) {
        int lrow = wr + i * 16 + q4 + r;
        size_t rb = (size_t)(row0 + lrow) * N + cb;
#pragma unroll
        for (int j = 0; j < 4; ++j) {
          float v = acc[i][j][r];
          if (mode == 1) v = 1.f / (1.f + __expf(-v));
          u16 vb = f2bf(v);
          C[rb + j * 16] = vb;
          if (jb.sym) Ts[(wc + j * 16 + l15) * 136 + lrow] = vb;
        }
      }
    if (jb.sym && tx != ty) {
      __syncthreads();
      int rr = tid >> 1, hf = (tid & 1) << 6;
      size_t rb2 = (size_t)(col0 + rr) * N + row0 + hf;
#pragma unroll
      for (int k = 0; k < 8; ++k)
        *(uint4*)(C + rb2 + k * 8) = *(const uint4*)(Ts + rr * 136 + hf + k * 8);
    }
  } else if (mode == 4) {
    u16* C  = (u16*)WSv + jb.c0;
    u16* CT = (u16*)WSv + jb.c1;
    const int M = jb.M;
#pragma unroll
    for (int i = 0; i < 4; ++i)
#pragma unroll
      for (int r = 0; r < 4; ++r) {
        int gr = row0 + wr + i * 16 + q4 + r;
#pragma unroll
        for (int j = 0; j < 4; ++j) {
          u16 v = f2bf(acc[i][j][r]);
          int gc = cb + j * 16;
          C[(size_t)gr * N + gc] = v;
          CT[(size_t)gc * M + gr] = v;
        }
      }
  } else {  // mode 3: adaptive dtype store into d_out
    if (*flag) {
      u16* C = (u16*)OutO + jb.c0;
#pragma unroll
      for (int i = 0; i < 4; ++i)
#pragma unroll
        for (int r = 0; r < 4; ++r) {
          int lrow = wr + i * 16 + q4 + r;
          size_t rb = (size_t)(row0 + lrow) * N + cb;
#pragma unroll
          for (int j = 0; j < 4; ++j) {
            u16 vb = f2bf(acc[i][j][r]);
            C[rb + j * 16] = vb;
            if (jb.sym) Ts[(wc + j * 16 + l15) * 136 + lrow] = vb;
          }
        }
      if (jb.sym && tx != ty) {
        __syncthreads();
        int rr = tid >> 1, hf = (tid & 1) << 6;
        size_t rb2 = (size_t)(col0 + rr) * N + row0 + hf;
#pragma unroll
        for (int k = 0; k < 8; ++k)
          *(uint4*)(C + rb2 + k * 8) = *(const uint4*)(Ts + rr * 136 + hf + k * 8);
      }
    } else {
      float* C = (float*)OutO + jb.c0;
      // direct (upper-triangle) tile: coalesced 64B quarter-wave stores
#pragma unroll
      for (int i = 0; i < 4; ++i)
#pragma unroll
        for (int r = 0; r < 4; ++r) {
          int gr = row0 + wr + i * 16 + q4 + r;
          size_t rb = (size_t)gr * N + cb;
#pragma unroll
          for (int j = 0; j < 4; ++j) C[rb + j * 16] = acc[i][j][r];
        }
      // mirror tile: LDS-staged f32 transpose in two 64-column half-passes,
      // then fully-coalesced 128-float row writes.
      if (jb.sym && tx != ty) {
        float* Tf = (float*)smem;          // 64 x 132 f32 = 33792 B <= 34816 B
        const int whalf = w & 1;           // wave's column half (wc = whalf*64)
#pragma unroll
        for (int half = 0; half < 2; ++half) {
          __syncthreads();                  // smem (As/Bs or prev half) dead
          if (whalf == half) {
#pragma unroll
            for (int i = 0; i < 4; ++i)
#pragma unroll
              for (int j = 0; j < 4; ++j) {
                int cl = j * 16 + l15;      // column-local within this half
#pragma unroll
                for (int r = 0; r < 4; ++r)
                  Tf[cl * 132 + wr + i * 16 + q4 + r] = acc[i][j][r];
              }
          }
          __syncthreads();
          int cl = tid >> 2, chf = (tid & 3) << 5;   // 4 threads per row, 32 f ea
          size_t rb2 = (size_t)(col0 + half * 64 + cl) * N + row0 + chf;
          const float* src = Tf + cl * 132 + chf;
#pragma unroll
          for (int k = 0; k < 8; ++k)
            *(float4*)(C + rb2 + k * 4) = *(const float4*)(src + k * 4);
        }
      }
    }
  }
}

// =======================================================================
extern "C" void kernel_launch(void* const* d_in, const int* in_sizes, int n_in,
                              void* d_out, int out_size, void* d_ws, size_t ws_size,
                              hipStream_t stream) {
  const void* X    = d_in[0];
  const int*  rows = (const int*)d_in[1];
  const int*  cols = (const int*)d_in[2];
  const void* vals = d_in[3];
  const void* Wsh  = d_in[4];

  char* W = (char*)d_ws;
  u16*  Xb    = (u16*)(W + 0);
  u16*  WshT  = (u16*)(W + 4194304);
  u16*  WTb   = (u16*)(W + 4456448);
  u16*  WgTb  = (u16*)(W + 4849664);
  int*  rp    = (int*)(W + 5242880);
  int*  cp    = (int*)(W + 5275648);
  int*  rfill = (int*)(W + 5308416);
  int*  cfill = (int*)(W + 5324800);
  int2* rpack = (int2*)(W + 5341184);   // 1 MB
  int2* cpack = (int2*)(W + 6389760);   // 1 MB
  float* linWf = (float*)(W + 7438336);
  float* linbf = (float*)(W + 7442432);
  int*  flag  = (int*)(W + 7442560);
  u16*  hb    = (u16*)(W + 8388608);
  u16*  tmpb[3] = { (u16*)(W + 10485760), (u16*)(W + 12582912), (u16*)(W + 14680064) };
  u16*  z0b[3]  = { (u16*)(W + 16777216), (u16*)(W + 18874368), (u16*)(W + 20971520) };
  u16*  hpb[3]  = { (u16*)(W + 23068672), (u16*)(W + 25165824), (u16*)(W + 27262976) };
  u16*  hpT[3]  = { (u16*)(W + 29360128), (u16*)(W + 31457280), (u16*)(W + 33554432) };
  u16*  tTb     = (u16*)(W + 35651584);
  u16*  zbb[3]  = { (u16*)(W + 41943040), (u16*)(W + 44040192), (u16*)(W + 46137344) };
  u16*  ubb[3]  = { (u16*)(W + 48234496), (u16*)(W + 50331648), (u16*)(W + 52428800) };
  float* partf  = (float*)(W + 54525952);   // 48 MB split-K partials (also hist slabs)
  int*  slabs  = (int*)(W + 54525952);      // 1 MB, consumed before partials

  const long long z_off[3]   = { 0LL, 17825792LL, 35651584LL };
  const long long rec_off[3] = { 1048576LL, 18874368LL, 36700160LL };
  const long long mi_off = 53477376LL, pred_off = 53477377LL;

  const u16* r2p[3] = { (const u16*)d_out + rec_off[0], (const u16*)d_out + rec_off[1],
                        (const u16*)d_out + rec_off[2] };

  // 1. private-LDS histograms -> slabs
  hist_priv_k<<<32, 256, 0, stream>>>(rows, cols, slabs);
  // 2. scan + dtype detect + zero fills
  scan2_k<<<1, 1024, 0, stream>>>((const unsigned int*)X, slabs, rp, cp, rfill, cfill, flag);
  // 3. converts/transposes + scatter
  setup2_k<<<10757, 256, 0, stream>>>(X, Wsh, d_in[5], d_in[6], d_in[7],
                                      d_in[8], d_in[9], d_in[10], d_in[11], d_in[12],
                                      rows, cols, vals, rp, cp, rfill, cfill, rpack, cpack,
                                      Xb, WshT, WTb, WgTb, linWf, linbf, flag);

  Jobs P{};
  auto setj = [](Job& j, const u16* A, const u16* B, unsigned long long c0,
                 unsigned long long c1, unsigned long long ps, int M, int N, int K,
                 int mode, int nks, int sym) {
    j.A = A; j.B = B; j.F1 = nullptr; j.F2 = nullptr;
    j.c0 = c0; j.c1 = c1; j.pstride = ps;
    j.M = M; j.N = N; j.K = K; j.mode = mode;
    j.xt = N / 128;
    j.ntiles = sym ? (j.xt * (j.xt + 1)) / 2 : (M / 128) * (N / 128);
    j.nks = nks; j.kspan = K / nks; j.sym = sym;
  };

  // 4. J1: tmp0 = X @ Wsh
  setj(P.j[0], Xb, WshT, ((char*)tmpb[0] - W) / 2, 0, 0, Nn, HIDd, FINd, 0, 1, 0);
  gemm_mega<<<dim3(64, 1, 1), 256, 0, stream>>>(P, d_ws, d_out, flag);

  // 5. h = relu(A @ tmp0)
  SPP s{};
  s.ptr = rp; s.ep = rpack;
  s.m[0] = tmpb[0]; s.ob[0] = hb;
  spmm_mb_k<<<dim3(Nn / 4, 1), 256, 0, stream>>>(s, nullptr, nullptr, 0, flag);

  // 6. J2: tmp_b = h @ W_b
  for (int b = 0; b < 3; ++b)
    setj(P.j[b], hb, WTb + b * 65536, ((char*)tmpb[b] - W) / 2, 0, 0, Nn, HIDd, HIDd, 0, 1, 0);
  gemm_mega<<<dim3(64, 1, 3), 256, 0, stream>>>(P, d_ws, d_out, flag);

  // 7. z0_b = relu(A @ tmp_b)
  for (int b = 0; b < 3; ++b) { s.m[b] = tmpb[b]; s.ob[b] = z0b[b]; }
  spmm_mb_k<<<dim3(Nn / 4, 3), 256, 0, stream>>>(s, nullptr, nullptr, 0, flag);

  // 8. J3: r2_b = sigmoid(z0 z0^T) [SYM] + hp_b = z0 @ Wg_b [dual]
  for (int b = 0; b < 3; ++b) {
    setj(P.j[b], z0b[b], z0b[b], rec_off[b], 0, 0, Nn, Nn, HIDd, 1, 1, 1);
    setj(P.j[3 + b], z0b[b], WgTb + b * 65536, ((char*)hpb[b] - W) / 2,
         ((char*)hpT[b] - W) / 2, 0, Nn, HIDd, HIDd, 4, 1, 0);
  }
  gemm_mega<<<dim3(528, 1, 6), 256, 0, stream>>>(P, d_ws, d_out, flag);

  // 9. J4 (tall-A) + fused spmm-u: tT partials = h'^T @ r2 (128 blocks)
  //    + u_b = A^T @ hp_b (512 CSC gather blocks, overlap MFMA)
  TQ T{};
  for (int b = 0; b < 3; ++b) {
    T.Ap[b] = hpT[b]; T.Bp[b] = r2p[b];
    T.c0[b] = (unsigned long long)b * 1048576ULL;
    T.hp[b] = hpb[b]; T.ub[b] = ubb[b];
  }
  T.tallA = 1; T.K = Nn; T.N = Nn; T.kspan = 1024;
  T.cp = cp; T.cep = cpack;
  tall_spmmu_k<<<dim3(640, 1, 3), 512, 0, stream>>>(T, partf);

  // 10. redt (tT partials -> bf16)
  redt_k<<<3072, 256, 0, stream>>>(partf, tTb);

  // 11. J5 (tall-B): buf partials = r2 @ t, split-K=4 (no fused gather)
  TQ T2{};
  for (int b = 0; b < 3; ++b) {
    T2.Ap[b] = r2p[b]; T2.Bp[b] = tTb + b * 1048576;
    T2.c0[b] = (unsigned long long)b * 1048576ULL;
    T2.hp[b] = nullptr; T2.ub[b] = nullptr;
  }
  T2.tallA = 0; T2.K = Nn; T2.N = HIDd; T2.kspan = 1024;
  T2.cp = nullptr; T2.cep = nullptr;
  tall_spmmu_k<<<dim3(128, 1, 3), 512, 0, stream>>>(T2, partf);

  // 12. z_b = relu(sum4(buf parts) + A @ u_b) -> zbb + d_out
  for (int b = 0; b < 3; ++b) {
    s.m[b] = ubb[b];
    s.ob[b] = zbb[b]; s.oo[b] = (unsigned long long)z_off[b];
  }
  spmm_mb_k<<<dim3(Nn / 4, 3), 256, 0, stream>>>(s, partf, d_out, 2, flag);

  // 13. J6: zrec_b = z z^T -> d_out [SYM, adaptive] + head [mode 6]
  for (int b = 0; b < 3; ++b)
    setj(P.j[b], zbb[b], zbb[b], rec_off[b], 0, 0, Nn, Nn, HIDd, 3, 1, 1);
  setj(P.j[3], zbb[0], zbb[1], (unsigned long long)pred_off,
       (unsigned long long)mi_off, 0, 256, 128, 64, 6, 1, 0);
  P.j[3].ntiles = 16; P.j[3].nks = 1;
  P.j[3].F1 = linWf; P.j[3].F2 = linbf;
  gemm_mega<<<dim3(528, 1, 4), 256, 0, stream>>>(P, d_ws, d_out, flag);

  (void)in_sizes; (void)n_in; (void)out_size; (void)ws_size;
}

// Round 10
// 623.225 us; speedup vs baseline: 1.0850x; 1.0019x over previous
//
#include <hip/hip_runtime.h>

#define Nn   4096
#define FINd 512
#define HIDd 256
#define NEd  131072

typedef unsigned short u16;
typedef __bf16 bf16x8 __attribute__((ext_vector_type(8)));
typedef float floatx4 __attribute__((ext_vector_type(4)));

// ---------------- bf16 helpers ----------------
__device__ __forceinline__ float bf2f(u16 u) {
  union { unsigned int i; float f; } v; v.i = ((unsigned int)u) << 16; return v.f;
}
__device__ __forceinline__ u16 f2bf(float f) {
  union { unsigned int i; float f; } v; v.f = f;
  unsigned int x = v.i;
  return (u16)((x + 0x7FFFu + ((x >> 16) & 1u)) >> 16);  // RNE
}

#define GLDS(gp, lp) __builtin_amdgcn_global_load_lds( \
    (__attribute__((address_space(1))) unsigned int*)(void*)(gp), \
    (__attribute__((address_space(3))) unsigned int*)(lp), 16, 0, 0)

// 4-edge gather step, order-preserving (sequential fmaf nesting)
#define GATH4(EP, M, F, AX, AY, AZ, AW, E)                                     \
  {                                                                            \
    int2 c0 = (EP)[E]; int2 c1 = (EP)[(E) + 1];                                \
    int2 c2 = (EP)[(E) + 2]; int2 c3 = (EP)[(E) + 3];                          \
    ushort4 m0 = *(const ushort4*)((M) + (size_t)c0.x * HIDd + (F));           \
    ushort4 m1 = *(const ushort4*)((M) + (size_t)c1.x * HIDd + (F));           \
    ushort4 m2 = *(const ushort4*)((M) + (size_t)c2.x * HIDd + (F));           \
    ushort4 m3 = *(const ushort4*)((M) + (size_t)c3.x * HIDd + (F));           \
    float v0 = __int_as_float(c0.y), v1 = __int_as_float(c1.y);                \
    float v2 = __int_as_float(c2.y), v3 = __int_as_float(c3.y);                \
    AX = fmaf(v3, bf2f(m3.x), fmaf(v2, bf2f(m2.x), fmaf(v1, bf2f(m1.x), fmaf(v0, bf2f(m0.x), AX)))); \
    AY = fmaf(v3, bf2f(m3.y), fmaf(v2, bf2f(m2.y), fmaf(v1, bf2f(m1.y), fmaf(v0, bf2f(m0.y), AY)))); \
    AZ = fmaf(v3, bf2f(m3.z), fmaf(v2, bf2f(m2.z), fmaf(v1, bf2f(m1.z), fmaf(v0, bf2f(m0.z), AZ)))); \
    AW = fmaf(v3, bf2f(m3.w), fmaf(v2, bf2f(m2.w), fmaf(v1, bf2f(m1.w), fmaf(v0, bf2f(m0.w), AW)))); \
  }

// 8-edge gather step: all 8 edge descs + all 8 row loads issued before the
// ordered FMA chain (sequential e..e+7 nesting -> bit-identical summation).
#define GATH8(EP, M, F, AX, AY, AZ, AW, E)                                     \
  {                                                                            \
    int2 c0 = (EP)[E];       int2 c1 = (EP)[(E) + 1];                          \
    int2 c2 = (EP)[(E) + 2]; int2 c3 = (EP)[(E) + 3];                          \
    int2 c4 = (EP)[(E) + 4]; int2 c5 = (EP)[(E) + 5];                          \
    int2 c6 = (EP)[(E) + 6]; int2 c7 = (EP)[(E) + 7];                          \
    ushort4 m0 = *(const ushort4*)((M) + (size_t)c0.x * HIDd + (F));           \
    ushort4 m1 = *(const ushort4*)((M) + (size_t)c1.x * HIDd + (F));           \
    ushort4 m2 = *(const ushort4*)((M) + (size_t)c2.x * HIDd + (F));           \
    ushort4 m3 = *(const ushort4*)((M) + (size_t)c3.x * HIDd + (F));           \
    ushort4 m4 = *(const ushort4*)((M) + (size_t)c4.x * HIDd + (F));           \
    ushort4 m5 = *(const ushort4*)((M) + (size_t)c5.x * HIDd + (F));           \
    ushort4 m6 = *(const ushort4*)((M) + (size_t)c6.x * HIDd + (F));           \
    ushort4 m7 = *(const ushort4*)((M) + (size_t)c7.x * HIDd + (F));           \
    float v0 = __int_as_float(c0.y), v1 = __int_as_float(c1.y);                \
    float v2 = __int_as_float(c2.y), v3 = __int_as_float(c3.y);                \
    float v4 = __int_as_float(c4.y), v5 = __int_as_float(c5.y);                \
    float v6 = __int_as_float(c6.y), v7 = __int_as_float(c7.y);                \
    AX = fmaf(v7, bf2f(m7.x), fmaf(v6, bf2f(m6.x), fmaf(v5, bf2f(m5.x), fmaf(v4, bf2f(m4.x), \
         fmaf(v3, bf2f(m3.x), fmaf(v2, bf2f(m2.x), fmaf(v1, bf2f(m1.x), fmaf(v0, bf2f(m0.x), AX)))))))); \
    AY = fmaf(v7, bf2f(m7.y), fmaf(v6, bf2f(m6.y), fmaf(v5, bf2f(m5.y), fmaf(v4, bf2f(m4.y), \
         fmaf(v3, bf2f(m3.y), fmaf(v2, bf2f(m2.y), fmaf(v1, bf2f(m1.y), fmaf(v0, bf2f(m0.y), AY)))))))); \
    AZ = fmaf(v7, bf2f(m7.z), fmaf(v6, bf2f(m6.z), fmaf(v5, bf2f(m5.z), fmaf(v4, bf2f(m4.z), \
         fmaf(v3, bf2f(m3.z), fmaf(v2, bf2f(m2.z), fmaf(v1, bf2f(m1.z), fmaf(v0, bf2f(m0.z), AZ)))))))); \
    AW = fmaf(v7, bf2f(m7.w), fmaf(v6, bf2f(m6.w), fmaf(v5, bf2f(m5.w), fmaf(v4, bf2f(m4.w), \
         fmaf(v3, bf2f(m3.w), fmaf(v2, bf2f(m2.w), fmaf(v1, bf2f(m1.w), fmaf(v0, bf2f(m0.w), AW)))))))); \
  }

// ---------------- private-LDS histogram -> slabs (no global atomics) ----------
__global__ __launch_bounds__(256) void hist_priv_k(const int* __restrict__ rows,
                                                   const int* __restrict__ cols,
                                                   int* __restrict__ slabs) {
  __shared__ int cnt[8192];
  const int t = threadIdx.x;
  for (int i = t; i < 8192; i += 256) cnt[i] = 0;
  __syncthreads();
  int base = blockIdx.x * 4096;
  for (int i = t; i < 4096; i += 256) {
    int e = base + i;
    atomicAdd(&cnt[rows[e]], 1);
    atomicAdd(&cnt[4096 + cols[e]], 1);
  }
  __syncthreads();
  int* out = slabs + blockIdx.x * 8192;
  for (int i = t; i < 8192; i += 256) out[i] = cnt[i];
}

// ---------------- scan (sum 32 slabs -> rp/cp) + dtype detect + zero fills ------
__global__ __launch_bounds__(1024) void scan2_k(const unsigned int* __restrict__ X,
                                                const int* __restrict__ slabs,
                                                int* __restrict__ rp, int* __restrict__ cp,
                                                int* __restrict__ rfill, int* __restrict__ cfill,
                                                int* __restrict__ flag) {
  __shared__ int part[1024];
  __shared__ int dcnt;
  const int t = threadIdx.x;
  if (t == 0) dcnt = 0;
  __syncthreads();
  int local = 0;
  for (int i = t; i < 4096; i += 1024) {
    unsigned e = (X[i] >> 7) & 0xFFu;
    if (e >= 100u && e <= 140u) local++;
  }
  if (local) atomicAdd(&dcnt, local);
  int base = t * 8, s = 0, loc[8];
  int csum[8];
#pragma unroll
  for (int j = 0; j < 8; ++j) csum[j] = 0;
  for (int sl = 0; sl < 32; ++sl) {
    const int* sp = slabs + sl * 8192 + base;
#pragma unroll
    for (int j = 0; j < 8; ++j) csum[j] += sp[j];
  }
#pragma unroll
  for (int j = 0; j < 8; ++j) { loc[j] = s; s += csum[j]; }
  part[t] = s;
  __syncthreads();
  if (t == 0) *flag = (dcnt > 2458) ? 1 : 0;
  for (int off = 1; off < 1024; off <<= 1) {
    int v = (t >= off) ? part[t - off] : 0;
    __syncthreads();
    part[t] += v;
    __syncthreads();
  }
  int excl = (t == 0) ? 0 : part[t - 1];
  int rtot = part[511];
  if (t < 512) {
#pragma unroll
    for (int j = 0; j < 8; ++j) rp[base + j] = excl + loc[j];
    if (t == 511) rp[4096] = rtot;
  } else {
    int cb = base - 4096;
    int ex2 = excl - rtot;
#pragma unroll
    for (int j = 0; j < 8; ++j) cp[cb + j] = ex2 + loc[j];
    if (t == 1023) cp[4096] = part[1023] - rtot;
  }
  for (int i = t; i < 4096; i += 1024) { rfill[i] = 0; cfill[i] = 0; }
}

// ---------------- converts/transposes + CSR/CSC scatter, one kernel ----------------
__global__ __launch_bounds__(256) void setup2_k(const void* __restrict__ X,
                                                const void* __restrict__ Wsh,
                                                const void* __restrict__ W0, const void* __restrict__ W1,
                                                const void* __restrict__ W2, const void* __restrict__ G0,
                                                const void* __restrict__ G1, const void* __restrict__ G2,
                                                const void* __restrict__ linW, const void* __restrict__ linb,
                                                const int* __restrict__ rows, const int* __restrict__ cols,
                                                const void* __restrict__ vals,
                                                const int* __restrict__ rp, const int* __restrict__ cp,
                                                int* __restrict__ rfill, int* __restrict__ cfill,
                                                int2* __restrict__ rpack, int2* __restrict__ cpack,
                                                u16* __restrict__ Xb, u16* __restrict__ WshT,
                                                u16* __restrict__ WTb, u16* __restrict__ WgTb,
                                                float* __restrict__ linWf, float* __restrict__ linbf,
                                                const int* __restrict__ flag) {
  int fl = *flag;
  int bx = blockIdx.x;
  if (bx >= 10245) {  // scatter part
    int e = (bx - 10245) * 256 + threadIdx.x;
    if (e >= NEd) return;
    float v = fl ? bf2f(((const u16*)vals)[e]) : ((const float*)vals)[e];
    int r = rows[e], c = cols[e];
    int p1 = rp[r] + atomicAdd(&rfill[r], 1);
    rpack[p1] = make_int2(c, __float_as_int(v));
    int p2 = cp[c] + atomicAdd(&cfill[c], 1);
    cpack[p2] = make_int2(r, __float_as_int(v));
    return;
  }
  int i = bx * 256 + threadIdx.x;
  if (i < 2097152) {
    Xb[i] = fl ? ((const u16*)X)[i] : f2bf(((const float*)X)[i]);
    return;
  }
  int i2 = i - 2097152;
  if (i2 < 131072) {
    int r = i2 >> 8, c = i2 & 255;
    u16 v = fl ? ((const u16*)Wsh)[i2] : f2bf(((const float*)Wsh)[i2]);
    WshT[c * 512 + r] = v;
    return;
  }
  int i3 = i2 - 131072;
  if (i3 < 393216) {
    int w = i3 >> 16, j = i3 & 65535;
    int r = j >> 8, c = j & 255;
    const void* src = (w == 0) ? W0 : (w == 1) ? W1 : (w == 2) ? W2
                     : (w == 3) ? G0 : (w == 4) ? G1 : G2;
    u16 v = fl ? ((const u16*)src)[j] : f2bf(((const float*)src)[j]);
    u16* dst = (w < 3) ? (WTb + w * 65536) : (WgTb + (w - 3) * 65536);
    dst[c * 256 + r] = v;
    return;
  }
  int i4 = i3 - 393216;
  if (i4 < 1024) { linWf[i4] = fl ? bf2f(((const u16*)linW)[i4]) : ((const float*)linW)[i4]; return; }
  if (i4 < 1026) { int k = i4 - 1024; linbf[k] = fl ? bf2f(((const u16*)linb)[k]) : ((const float*)linb)[k]; }
}

// ---------------- batched SpMM (CSR, int2 edges, bf16 gather, f32 accum) --------
// edge loop unrolled x8 (then x4, then singles): all loads of a group issued
// before its ordered FMAs; sequential fmaf nesting -> bit-identical sums.
struct SPP {
  const int* ptr; const int2* ep;
  const u16* m[3]; u16* ob[3]; unsigned long long oo[3];
};
__global__ __launch_bounds__(256) void spmm_mb_k(SPP s, const float* __restrict__ part,
                                                 void* __restrict__ outbase, int mode,
                                                 const int* __restrict__ flag) {
  const int b = blockIdx.y;
  int gid = blockIdx.x * 256 + threadIdx.x;
  int row = gid >> 6, lane = gid & 63, f = lane << 2;
  int beg = s.ptr[row], end = s.ptr[row + 1];
  const u16* m = s.m[b];
  float ax = 0.f, ay = 0.f, az = 0.f, aw = 0.f;
  int e = beg;
  for (; e + 7 < end; e += 8) GATH8(s.ep, m, f, ax, ay, az, aw, e);
  for (; e + 3 < end; e += 4) GATH4(s.ep, m, f, ax, ay, az, aw, e);
  for (; e < end; ++e) {
    int2 cv = s.ep[e];
    float v = __int_as_float(cv.y);
    ushort4 mv = *(const ushort4*)(m + (size_t)cv.x * HIDd + f);
    ax = fmaf(v, bf2f(mv.x), ax);
    ay = fmaf(v, bf2f(mv.y), ay);
    az = fmaf(v, bf2f(mv.z), az);
    aw = fmaf(v, bf2f(mv.w), aw);
  }
  size_t o = (size_t)row * HIDd + f;
  if (mode == 2) {
    const float* pb = part + (size_t)b * 1048576 + o;
    float4 p0 = *(const float4*)(pb);
    float4 p1 = *(const float4*)(pb + 3145728);
    float4 p2 = *(const float4*)(pb + 2 * 3145728);
    float4 p3 = *(const float4*)(pb + 3 * 3145728);
    ax += p0.x + p1.x + p2.x + p3.x;
    ay += p0.y + p1.y + p2.y + p3.y;
    az += p0.z + p1.z + p2.z + p3.z;
    aw += p0.w + p1.w + p2.w + p3.w;
    ax = fmaxf(ax, 0.f); ay = fmaxf(ay, 0.f);
    az = fmaxf(az, 0.f); aw = fmaxf(aw, 0.f);
    ushort4 o4 = { f2bf(ax), f2bf(ay), f2bf(az), f2bf(aw) };
    *(ushort4*)(s.ob[b] + o) = o4;
    if (*flag) *(ushort4*)((u16*)outbase + s.oo[b] + o) = o4;
    else       *(float4*)((float*)outbase + s.oo[b] + o) = make_float4(ax, ay, az, aw);
  } else {
    if (mode == 0) {
      ax = fmaxf(ax, 0.f); ay = fmaxf(ay, 0.f);
      az = fmaxf(az, 0.f); aw = fmaxf(aw, 0.f);
    }
    ushort4 o4 = { f2bf(ax), f2bf(ay), f2bf(az), f2bf(aw) };
    *(ushort4*)(s.ob[b] + o) = o4;
  }
}

// ---------------- redt only (tT partial reduce) ----------------
__global__ __launch_bounds__(256) void redt_k(const float* __restrict__ part,
                                              u16* __restrict__ tT) {
  int i = (blockIdx.x * 256 + threadIdx.x) * 4;
  float4 s0 = *(const float4*)(part + i);
  float4 s1 = *(const float4*)(part + i + 3145728);
  float4 s2 = *(const float4*)(part + i + 2 * 3145728);
  float4 s3 = *(const float4*)(part + i + 3 * 3145728);
  ushort4 o = { f2bf(s0.x + s1.x + s2.x + s3.x), f2bf(s0.y + s1.y + s2.y + s3.y),
                f2bf(s0.z + s1.z + s2.z + s3.z), f2bf(s0.w + s1.w + s2.w + s3.w) };
  *(ushort4*)(tT + i) = o;
}

// ---------------- tall-tile split-K GEMM + fused spmm-u (J4) ------
// blockIdx.x <  128 : tall GEMM (J4/J5 structure, unchanged arithmetic)
// blockIdx.x >= 128 : CSC spmm-u gather blocks (512 thr = 8 rows), J4 launch only.
// The gather depends only on hp (ready before this dispatch) -> overlaps MFMA.
struct TQ {
  const u16* Ap[3]; const u16* Bp[3]; unsigned long long c0[3];
  int tallA, K, N, kspan;
  const int* cp; const int2* cep;
  const u16* hp[3]; u16* ub[3];
};

__global__ __launch_bounds__(512) void tall_spmmu_k(TQ P, float* __restrict__ partf) {
  __shared__ __align__(16) u16 smem[24576];   // 48 KB
  const int b = blockIdx.z;
  const int bx = blockIdx.x;
  if (bx >= 128) {
    // ---- fused spmm-u: u_b = A^T @ hp_b (CSC), bf16 store ----
    int gid = (bx - 128) * 512 + threadIdx.x;
    int row = gid >> 6, lane = gid & 63, f = lane << 2;
    int beg = P.cp[row], end = P.cp[row + 1];
    const u16* m = P.hp[b];
    float ax = 0.f, ay = 0.f, az = 0.f, aw = 0.f;
    int e = beg;
    for (; e + 3 < end; e += 4) GATH4(P.cep, m, f, ax, ay, az, aw, e);
    for (; e < end; ++e) {
      int2 cv = P.cep[e];
      float v = __int_as_float(cv.y);
      ushort4 mv = *(const ushort4*)(m + (size_t)cv.x * HIDd + f);
      ax = fmaf(v, bf2f(mv.x), ax);
      ay = fmaf(v, bf2f(mv.y), ay);
      az = fmaf(v, bf2f(mv.z), az);
      aw = fmaf(v, bf2f(mv.w), aw);
    }
    size_t o = (size_t)row * HIDd + f;
    ushort4 o4 = { f2bf(ax), f2bf(ay), f2bf(az), f2bf(aw) };
    *(ushort4*)(P.ub[b] + o) = o4;
    return;
  }
  // ---- tall GEMM ----
  const u16* A = P.Ap[b];
  const u16* B = P.Bp[b];
  const int K = P.K, N = P.N, tallA = P.tallA;
  const int stripe = bx & 31, ks = bx >> 5;
  const int tid = threadIdx.x, w = tid >> 6, lane = tid & 63;
  const int lr = lane >> 3, cc = lane & 7;
  const int scol = (cc ^ lr) << 3;
  u16* As = smem;
  u16* Bs = smem + (tallA ? 16384 : 8192);
  int wrow, wcol;
  if (tallA) { wrow = (w >> 1) * 64; wcol = (w & 1) * 64; }
  else       { wrow = (w >> 2) * 64; wcol = (w & 3) * 64; }
  const int row0 = tallA ? 0 : stripe * 128;
  const int col0 = tallA ? stripe * 128 : 0;
  const int na = tallA ? 4 : 2;   // A chunks (1 KB) per wave
  const int nb = tallA ? 2 : 4;   // B chunks per wave
  floatx4 acc[4][4] = {};
  int aoff[4], boff[4];
#pragma unroll
  for (int i = 0; i < 4; ++i) {
    int m = wrow + i * 16 + (lane & 15);        // local A row
    aoff[i] = m * 64 + (((lane >> 4) << 3) ^ ((m & 7) << 3));
    int n = wcol + i * 16 + (lane & 15);        // local B row
    boff[i] = n * 64 + (((lane >> 4) << 3) ^ ((n & 7) << 3));
  }
  const int kbeg = ks * P.kspan, kend = kbeg + P.kspan;
  for (int k0 = kbeg; k0 < kend; k0 += 64) {
#pragma unroll
    for (int t = 0; t < 4; ++t) {
      if (t < na) {
        int ch = na * w + t;
        GLDS(A + (size_t)(row0 + 8 * ch + lr) * K + k0 + scol, As + ch * 512);
      }
      if (t < nb) {
        int ch = nb * w + t;
        GLDS(B + (size_t)(col0 + 8 * ch + lr) * K + k0 + scol, Bs + ch * 512);
      }
    }
    __syncthreads();
#pragma unroll
    for (int kk = 0; kk < 2; ++kk) {
      bf16x8 af[4], bfr[4];
#pragma unroll
      for (int i = 0; i < 4; ++i) {
        af[i]  = *(const bf16x8*)(As + (aoff[i] ^ (kk << 5)));
        bfr[i] = *(const bf16x8*)(Bs + (boff[i] ^ (kk << 5)));
      }
#pragma unroll
      for (int i = 0; i < 4; ++i)
#pragma unroll
        for (int j = 0; j < 4; ++j)
          acc[i][j] = __builtin_amdgcn_mfma_f32_16x16x32_bf16(af[i], bfr[j], acc[i][j], 0, 0, 0);
    }
    __syncthreads();
  }
  const int l15 = lane & 15, q4 = (lane >> 4) << 2;
  float* C = partf + P.c0[b] + (size_t)ks * 3145728;
  const int cbase = col0 + wcol + l15;
#pragma unroll
  for (int i = 0; i < 4; ++i)
#pragma unroll
    for (int r = 0; r < 4; ++r) {
      size_t rb = (size_t)(row0 + wrow + i * 16 + q4 + r) * N + cbase;
#pragma unroll
      for (int j = 0; j < 4; ++j) C[rb + j * 16] = acc[i][j][r];
    }
}

// ---------------- job-table bf16 MFMA NT GEMM ----------------
// modes: 0 bf16->ws; 1 sigmoid->bf16 d_out; 3 adaptive d_out; 4 dual bf16->ws;
//        6 head (log_softmax). sym: upper tiles + mirror.
struct Job {
  const u16* A; const u16* B;
  const float* F1; const float* F2;
  unsigned long long c0, c1, pstride;
  int M, N, K, mode, xt, ntiles, nks, kspan, sym;
};
struct Jobs { Job j[6]; };

__global__ __launch_bounds__(256) void gemm_mega(Jobs P, void* __restrict__ WSv,
                                                 void* __restrict__ OutO,
                                                 const int* __restrict__ flag) {
  __shared__ __align__(16) u16 smem[17408];
  u16* As = smem;
  u16* Bs = smem + 8192;
  u16* Ts = smem;
  const Job jb = P.j[blockIdx.z];
  const unsigned tile = blockIdx.x;
  if ((int)tile >= jb.ntiles * jb.nks) return;
  if (jb.mode == 6) {  // head: pred_T = log_softmax([ziv|zc] @ lw + lb)
    int i = tile * 256 + threadIdx.x;
    const float* lw = jb.F1;
    float a0 = jb.F2[0], a1 = jb.F2[1];
    for (int f = 0; f < HIDd; ++f) {
      float zv = bf2f(jb.A[(size_t)i * HIDd + f]);
      a0 = fmaf(zv, lw[2 * f + 0], a0);
      a1 = fmaf(zv, lw[2 * f + 1], a1);
    }
    for (int f = 0; f < HIDd; ++f) {
      float zv = bf2f(jb.B[(size_t)i * HIDd + f]);
      a0 = fmaf(zv, lw[2 * (HIDd + f) + 0], a0);
      a1 = fmaf(zv, lw[2 * (HIDd + f) + 1], a1);
    }
    float mx = fmaxf(a0, a1);
    float lse = mx + logf(expf(a0 - mx) + expf(a1 - mx));
    float p0 = a0 - lse, p1 = a1 - lse;
    if (*flag) {
      u16* ob = (u16*)OutO;
      ob[jb.c0 + 2 * i + 0] = f2bf(p0);
      ob[jb.c0 + 2 * i + 1] = f2bf(p1);
      if (i == 0) ob[jb.c1] = 0;
    } else {
      float* ob = (float*)OutO;
      ob[jb.c0 + 2 * i + 0] = p0;
      ob[jb.c0 + 2 * i + 1] = p1;
      if (i == 0) ob[jb.c1] = 0.f;
    }
    return;
  }
  const unsigned ks = tile / (unsigned)jb.ntiles;
  const unsigned t2 = tile - ks * jb.ntiles;
  unsigned ty, tx;
  if (jb.sym) {
    unsigned rem = t2, rowlen = jb.xt; ty = 0;
    while (rem >= rowlen) { rem -= rowlen; --rowlen; ++ty; }
    tx = ty + rem;
  } else {
    ty = t2 / (unsigned)jb.xt;
    tx = t2 - ty * jb.xt;
  }
  const int K = jb.K, N = jb.N;
  const int row0 = ty * 128, col0 = tx * 128;
  const int tid = threadIdx.x;
  const int w = tid >> 6, lane = tid & 63;
  const int wr = (w >> 1) * 64, wc = (w & 1) * 64;
  const int lr = lane >> 3, cc = lane & 7;
  const int scol = (cc ^ lr) << 3;
  floatx4 acc[4][4] = {};
  int aoff[4], boff[4];
#pragma unroll
  for (int i = 0; i < 4; ++i) {
    int m = wr + i * 16 + (lane & 15);
    aoff[i] = m * 64 + ((((lane >> 4) << 3)) ^ ((m & 7) << 3));
    int n = wc + i * 16 + (lane & 15);
    boff[i] = n * 64 + ((((lane >> 4) << 3)) ^ ((n & 7) << 3));
  }
  const u16* A = jb.A;
  const u16* B = jb.B;
  const int kbeg = ks * jb.kspan, kend = kbeg + jb.kspan;
  for (int k0 = kbeg; k0 < kend; k0 += 64) {
#pragma unroll
    for (int t = 0; t < 4; ++t) {
      int ch = 4 * w + t;
      GLDS(A + (size_t)(row0 + 8 * ch + lr) * K + k0 + scol, As + ch * 512);
      GLDS(B + (size_t)(col0 + 8 * ch + lr) * K + k0 + scol, Bs + ch * 512);
    }
    __syncthreads();
#pragma unroll
    for (int kk = 0; kk < 2; ++kk) {
      bf16x8 af[4], bfr[4];
#pragma unroll
      for (int i = 0; i < 4; ++i) {
        af[i]  = *(const bf16x8*)(As + (aoff[i] ^ (kk << 5)));
        bfr[i] = *(const bf16x8*)(Bs + (boff[i] ^ (kk << 5)));
      }
#pragma unroll
      for (int i = 0; i < 4; ++i)
#pragma unroll
        for (int j = 0; j < 4; ++j)
          acc[i][j] = __builtin_amdgcn_mfma_f32_16x16x32_bf16(af[i], bfr[j], acc[i][j], 0, 0, 0);
    }
    __syncthreads();
  }

  const int l15 = lane & 15, q4 = (lane >> 4) << 2;
  const int cb = col0 + wc + l15;
  const int mode = jb.mode;
  if (mode == 0 || mode == 1) {
    u16* C = ((mode == 1) ? (u16*)OutO : (u16*)WSv) + jb.c0;
#pragma unroll
    for (int i = 0; i < 4; ++i)
#pragma unroll
      for (int r = 0; r < 4; ++r) {
        int lrow = wr + i * 16 + q4 + r;
        size_t rb = (size_t)(row0 + lrow) * N + cb;
#pragma unroll
        for (int j = 0; j < 4; ++j) {
          float v = acc[i][j][r];
          if (mode == 1) v = 1.f / (1.f + __expf(-v));
          u16 vb = f2bf(v);
          C[rb + j * 16] = vb;
          if (jb.sym) Ts[(wc + j * 16 + l15) * 136 + lrow] = vb;
        }
      }
    if (jb.sym && tx != ty) {
      __syncthreads();
      int rr = tid >> 1, hf = (tid & 1) << 6;
      size_t rb2 = (size_t)(col0 + rr) * N + row0 + hf;
#pragma unroll
      for (int k = 0; k < 8; ++k)
        *(uint4*)(C + rb2 + k * 8) = *(const uint4*)(Ts + rr * 136 + hf + k * 8);
    }
  } else if (mode == 4) {
    u16* C  = (u16*)WSv + jb.c0;
    u16* CT = (u16*)WSv + jb.c1;
    const int M = jb.M;
#pragma unroll
    for (int i = 0; i < 4; ++i)
#pragma unroll
      for (int r = 0; r < 4; ++r) {
        int gr = row0 + wr + i * 16 + q4 + r;
#pragma unroll
        for (int j = 0; j < 4; ++j) {
          u16 v = f2bf(acc[i][j][r]);
          int gc = cb + j * 16;
          C[(size_t)gr * N + gc] = v;
          CT[(size_t)gc * M + gr] = v;
        }
      }
  } else {  // mode 3: adaptive dtype store into d_out
    if (*flag) {
      u16* C = (u16*)OutO + jb.c0;
#pragma unroll
      for (int i = 0; i < 4; ++i)
#pragma unroll
        for (int r = 0; r < 4; ++r) {
          int lrow = wr + i * 16 + q4 + r;
          size_t rb = (size_t)(row0 + lrow) * N + cb;
#pragma unroll
          for (int j = 0; j < 4; ++j) {
            u16 vb = f2bf(acc[i][j][r]);
            C[rb + j * 16] = vb;
            if (jb.sym) Ts[(wc + j * 16 + l15) * 136 + lrow] = vb;
          }
        }
      if (jb.sym && tx != ty) {
        __syncthreads();
        int rr = tid >> 1, hf = (tid & 1) << 6;
        size_t rb2 = (size_t)(col0 + rr) * N + row0 + hf;
#pragma unroll
        for (int k = 0; k < 8; ++k)
          *(uint4*)(C + rb2 + k * 8) = *(const uint4*)(Ts + rr * 136 + hf + k * 8);
      }
    } else {
      float* C = (float*)OutO + jb.c0;
      // direct (upper-triangle) tile: coalesced 64B quarter-wave stores
#pragma unroll
      for (int i = 0; i < 4; ++i)
#pragma unroll
      for (int r = 0; r < 4; ++r) {
          int gr = row0 + wr + i * 16 + q4 + r;
          size_t rb = (size_t)gr * N + cb;
#pragma unroll
          for (int j = 0; j < 4; ++j) C[rb + j * 16] = acc[i][j][r];
        }
      // mirror tile: LDS-staged f32 transpose in two 64-column half-passes,
      // then fully-coalesced 128-float row writes.
      if (jb.sym && tx != ty) {
        float* Tf = (float*)smem;          // 64 x 132 f32 = 33792 B <= 34816 B
        const int whalf = w & 1;           // wave's column half (wc = whalf*64)
#pragma unroll
        for (int half = 0; half < 2; ++half) {
          __syncthreads();                  // smem (As/Bs or prev half) dead
          if (whalf == half) {
#pragma unroll
            for (int i = 0; i < 4; ++i)
#pragma unroll
              for (int j = 0; j < 4; ++j) {
                int cl = j * 16 + l15;      // column-local within this half
#pragma unroll
                for (int r = 0; r < 4; ++r)
                  Tf[cl * 132 + wr + i * 16 + q4 + r] = acc[i][j][r];
              }
          }
          __syncthreads();
          int cl = tid >> 2, chf = (tid & 3) << 5;   // 4 threads per row, 32 f ea
          size_t rb2 = (size_t)(col0 + half * 64 + cl) * N + row0 + chf;
          const float* src = Tf + cl * 132 + chf;
#pragma unroll
          for (int k = 0; k < 8; ++k)
            *(float4*)(C + rb2 + k * 4) = *(const float4*)(src + k * 4);
        }
      }
    }
  }
}

// =======================================================================
extern "C" void kernel_launch(void* const* d_in, const int* in_sizes, int n_in,
                              void* d_out, int out_size, void* d_ws, size_t ws_size,
                              hipStream_t stream) {
  const void* X    = d_in[0];
  const int*  rows = (const int*)d_in[1];
  const int*  cols = (const int*)d_in[2];
  const void* vals = d_in[3];
  const void* Wsh  = d_in[4];

  char* W = (char*)d_ws;
  u16*  Xb    = (u16*)(W + 0);
  u16*  WshT  = (u16*)(W + 4194304);
  u16*  WTb   = (u16*)(W + 4456448);
  u16*  WgTb  = (u16*)(W + 4849664);
  int*  rp    = (int*)(W + 5242880);
  int*  cp    = (int*)(W + 5275648);
  int*  rfill = (int*)(W + 5308416);
  int*  cfill = (int*)(W + 5324800);
  int2* rpack = (int2*)(W + 5341184);   // 1 MB
  int2* cpack = (int2*)(W + 6389760);   // 1 MB
  float* linWf = (float*)(W + 7438336);
  float* linbf = (float*)(W + 7442432);
  int*  flag  = (int*)(W + 7442560);
  u16*  hb    = (u16*)(W + 8388608);
  u16*  tmpb[3] = { (u16*)(W + 10485760), (u16*)(W + 12582912), (u16*)(W + 14680064) };
  u16*  z0b[3]  = { (u16*)(W + 16777216), (u16*)(W + 18874368), (u16*)(W + 20971520) };
  u16*  hpb[3]  = { (u16*)(W + 23068672), (u16*)(W + 25165824), (u16*)(W + 27262976) };
  u16*  hpT[3]  = { (u16*)(W + 29360128), (u16*)(W + 31457280), (u16*)(W + 33554432) };
  u16*  tTb     = (u16*)(W + 35651584);
  u16*  zbb[3]  = { (u16*)(W + 41943040), (u16*)(W + 44040192), (u16*)(W + 46137344) };
  u16*  ubb[3]  = { (u16*)(W + 48234496), (u16*)(W + 50331648), (u16*)(W + 52428800) };
  float* partf  = (float*)(W + 54525952);   // 48 MB split-K partials (also hist slabs)
  int*  slabs  = (int*)(W + 54525952);      // 1 MB, consumed before partials

  const long long z_off[3]   = { 0LL, 17825792LL, 35651584LL };
  const long long rec_off[3] = { 1048576LL, 18874368LL, 36700160LL };
  const long long mi_off = 53477376LL, pred_off = 53477377LL;

  const u16* r2p[3] = { (const u16*)d_out + rec_off[0], (const u16*)d_out + rec_off[1],
                        (const u16*)d_out + rec_off[2] };

  // 1. private-LDS histograms -> slabs
  hist_priv_k<<<32, 256, 0, stream>>>(rows, cols, slabs);
  // 2. scan + dtype detect + zero fills
  scan2_k<<<1, 1024, 0, stream>>>((const unsigned int*)X, slabs, rp, cp, rfill, cfill, flag);
  // 3. converts/transposes + scatter
  setup2_k<<<10757, 256, 0, stream>>>(X, Wsh, d_in[5], d_in[6], d_in[7],
                                      d_in[8], d_in[9], d_in[10], d_in[11], d_in[12],
                                      rows, cols, vals, rp, cp, rfill, cfill, rpack, cpack,
                                      Xb, WshT, WTb, WgTb, linWf, linbf, flag);

  Jobs P{};
  auto setj = [](Job& j, const u16* A, const u16* B, unsigned long long c0,
                 unsigned long long c1, unsigned long long ps, int M, int N, int K,
                 int mode, int nks, int sym) {
    j.A = A; j.B = B; j.F1 = nullptr; j.F2 = nullptr;
    j.c0 = c0; j.c1 = c1; j.pstride = ps;
    j.M = M; j.N = N; j.K = K; j.mode = mode;
    j.xt = N / 128;
    j.ntiles = sym ? (j.xt * (j.xt + 1)) / 2 : (M / 128) * (N / 128);
    j.nks = nks; j.kspan = K / nks; j.sym = sym;
  };

  // 4. J1: tmp0 = X @ Wsh
  setj(P.j[0], Xb, WshT, ((char*)tmpb[0] - W) / 2, 0, 0, Nn, HIDd, FINd, 0, 1, 0);
  gemm_mega<<<dim3(64, 1, 1), 256, 0, stream>>>(P, d_ws, d_out, flag);

  // 5. h = relu(A @ tmp0)
  SPP s{};
  s.ptr = rp; s.ep = rpack;
  s.m[0] = tmpb[0]; s.ob[0] = hb;
  spmm_mb_k<<<dim3(Nn / 4, 1), 256, 0, stream>>>(s, nullptr, nullptr, 0, flag);

  // 6. J2: tmp_b = h @ W_b
  for (int b = 0; b < 3; ++b)
    setj(P.j[b], hb, WTb + b * 65536, ((char*)tmpb[b] - W) / 2, 0, 0, Nn, HIDd, HIDd, 0, 1, 0);
  gemm_mega<<<dim3(64, 1, 3), 256, 0, stream>>>(P, d_ws, d_out, flag);

  // 7. z0_b = relu(A @ tmp_b)
  for (int b = 0; b < 3; ++b) { s.m[b] = tmpb[b]; s.ob[b] = z0b[b]; }
  spmm_mb_k<<<dim3(Nn / 4, 3), 256, 0, stream>>>(s, nullptr, nullptr, 0, flag);

  // 8. J3: r2_b = sigmoid(z0 z0^T) [SYM] + hp_b = z0 @ Wg_b [dual]
  for (int b = 0; b < 3; ++b) {
    setj(P.j[b], z0b[b], z0b[b], rec_off[b], 0, 0, Nn, Nn, HIDd, 1, 1, 1);
    setj(P.j[3 + b], z0b[b], WgTb + b * 65536, ((char*)hpb[b] - W) / 2,
         ((char*)hpT[b] - W) / 2, 0, Nn, HIDd, HIDd, 4, 1, 0);
  }
  gemm_mega<<<dim3(528, 1, 6), 256, 0, stream>>>(P, d_ws, d_out, flag);

  // 9. J4 (tall-A) + fused spmm-u: tT partials = h'^T @ r2 (128 blocks)
  //    + u_b = A^T @ hp_b (512 CSC gather blocks, overlap MFMA)
  TQ T{};
  for (int b = 0; b < 3; ++b) {
    T.Ap[b] = hpT[b]; T.Bp[b] = r2p[b];
    T.c0[b] = (unsigned long long)b * 1048576ULL;
    T.hp[b] = hpb[b]; T.ub[b] = ubb[b];
  }
  T.tallA = 1; T.K = Nn; T.N = Nn; T.kspan = 1024;
  T.cp = cp; T.cep = cpack;
  tall_spmmu_k<<<dim3(640, 1, 3), 512, 0, stream>>>(T, partf);

  // 10. redt (tT partials -> bf16)
  redt_k<<<3072, 256, 0, stream>>>(partf, tTb);

  // 11. J5 (tall-B): buf partials = r2 @ t, split-K=4 (no fused gather)
  TQ T2{};
  for (int b = 0; b < 3; ++b) {
    T2.Ap[b] = r2p[b]; T2.Bp[b] = tTb + b * 1048576;
    T2.c0[b] = (unsigned long long)b * 1048576ULL;
    T2.hp[b] = nullptr; T2.ub[b] = nullptr;
  }
  T2.tallA = 0; T2.K = Nn; T2.N = HIDd; T2.kspan = 1024;
  T2.cp = nullptr; T2.cep = nullptr;
  tall_spmmu_k<<<dim3(128, 1, 3), 512, 0, stream>>>(T2, partf);

  // 12. z_b = relu(sum4(buf parts) + A @ u_b) -> zbb + d_out
  for (int b = 0; b < 3; ++b) {
    s.m[b] = ubb[b];
    s.ob[b] = zbb[b]; s.oo[b] = (unsigned long long)z_off[b];
  }
  spmm_mb_k<<<dim3(Nn / 4, 3), 256, 0, stream>>>(s, partf, d_out, 2, flag);

  // 13. J6: zrec_b = z z^T -> d_out [SYM, adaptive] + head [mode 6]
  for (int b = 0; b < 3; ++b)
    setj(P.j[b], zbb[b], zbb[b], rec_off[b], 0, 0, Nn, Nn, HIDd, 3, 1, 1);
  setj(P.j[3], zbb[0], zbb[1], (unsigned long long)pred_off,
       (unsigned long long)mi_off, 0, 256, 128, 64, 6, 1, 0);
  P.j[3].ntiles = 16; P.j[3].nks = 1;
  P.j[3].F1 = linWf; P.j[3].F2 = linbf;
  gemm_mega<<<dim3(528, 1, 4), 256, 0, stream>>>(P, d_ws, d_out, flag);

  (void)in_sizes; (void)n_in; (void)out_size; (void)ws_size;
}

// Round 11
// 603.955 us; speedup vs baseline: 1.1197x; 1.0319x over previous
//
#include <hip/hip_runtime.h>

#define Nn   4096
#define FINd 512
#define HIDd 256
#define NEd  131072

typedef unsigned short u16;
typedef __bf16 bf16x8 __attribute__((ext_vector_type(8)));
typedef float floatx4 __attribute__((ext_vector_type(4)));

// ---------------- bf16 helpers ----------------
__device__ __forceinline__ float bf2f(u16 u) {
  union { unsigned int i; float f; } v; v.i = ((unsigned int)u) << 16; return v.f;
}
__device__ __forceinline__ u16 f2bf(float f) {
  union { unsigned int i; float f; } v; v.f = f;
  unsigned int x = v.i;
  return (u16)((x + 0x7FFFu + ((x >> 16) & 1u)) >> 16);  // RNE
}

#define GLDS(gp, lp) __builtin_amdgcn_global_load_lds( \
    (__attribute__((address_space(1))) unsigned int*)(void*)(gp), \
    (__attribute__((address_space(3))) unsigned int*)(lp), 16, 0, 0)

// 4-edge gather step, order-preserving (sequential fmaf nesting)
#define GATH4(EP, M, F, AX, AY, AZ, AW, E)                                     \
  {                                                                            \
    int2 c0 = (EP)[E]; int2 c1 = (EP)[(E) + 1];                                \
    int2 c2 = (EP)[(E) + 2]; int2 c3 = (EP)[(E) + 3];                          \
    ushort4 m0 = *(const ushort4*)((M) + (size_t)c0.x * HIDd + (F));           \
    ushort4 m1 = *(const ushort4*)((M) + (size_t)c1.x * HIDd + (F));           \
    ushort4 m2 = *(const ushort4*)((M) + (size_t)c2.x * HIDd + (F));           \
    ushort4 m3 = *(const ushort4*)((M) + (size_t)c3.x * HIDd + (F));           \
    float v0 = __int_as_float(c0.y), v1 = __int_as_float(c1.y);                \
    float v2 = __int_as_float(c2.y), v3 = __int_as_float(c3.y);                \
    AX = fmaf(v3, bf2f(m3.x), fmaf(v2, bf2f(m2.x), fmaf(v1, bf2f(m1.x), fmaf(v0, bf2f(m0.x), AX)))); \
    AY = fmaf(v3, bf2f(m3.y), fmaf(v2, bf2f(m2.y), fmaf(v1, bf2f(m1.y), fmaf(v0, bf2f(m0.y), AY)))); \
    AZ = fmaf(v3, bf2f(m3.z), fmaf(v2, bf2f(m2.z), fmaf(v1, bf2f(m1.z), fmaf(v0, bf2f(m0.z), AZ)))); \
    AW = fmaf(v3, bf2f(m3.w), fmaf(v2, bf2f(m2.w), fmaf(v1, bf2f(m1.w), fmaf(v0, bf2f(m0.w), AW)))); \
  }

// 8-edge gather step: all 8 edge descs + all 8 row loads issued before the
// ordered FMA chain (sequential e..e+7 nesting -> bit-identical summation).
#define GATH8(EP, M, F, AX, AY, AZ, AW, E)                                     \
  {                                                                            \
    int2 c0 = (EP)[E];       int2 c1 = (EP)[(E) + 1];                          \
    int2 c2 = (EP)[(E) + 2]; int2 c3 = (EP)[(E) + 3];                          \
    int2 c4 = (EP)[(E) + 4]; int2 c5 = (EP)[(E) + 5];                          \
    int2 c6 = (EP)[(E) + 6]; int2 c7 = (EP)[(E) + 7];                          \
    ushort4 m0 = *(const ushort4*)((M) + (size_t)c0.x * HIDd + (F));           \
    ushort4 m1 = *(const ushort4*)((M) + (size_t)c1.x * HIDd + (F));           \
    ushort4 m2 = *(const ushort4*)((M) + (size_t)c2.x * HIDd + (F));           \
    ushort4 m3 = *(const ushort4*)((M) + (size_t)c3.x * HIDd + (F));           \
    ushort4 m4 = *(const ushort4*)((M) + (size_t)c4.x * HIDd + (F));           \
    ushort4 m5 = *(const ushort4*)((M) + (size_t)c5.x * HIDd + (F));           \
    ushort4 m6 = *(const ushort4*)((M) + (size_t)c6.x * HIDd + (F));           \
    ushort4 m7 = *(const ushort4*)((M) + (size_t)c7.x * HIDd + (F));           \
    float v0 = __int_as_float(c0.y), v1 = __int_as_float(c1.y);                \
    float v2 = __int_as_float(c2.y), v3 = __int_as_float(c3.y);                \
    float v4 = __int_as_float(c4.y), v5 = __int_as_float(c5.y);                \
    float v6 = __int_as_float(c6.y), v7 = __int_as_float(c7.y);                \
    AX = fmaf(v7, bf2f(m7.x), fmaf(v6, bf2f(m6.x), fmaf(v5, bf2f(m5.x), fmaf(v4, bf2f(m4.x), \
         fmaf(v3, bf2f(m3.x), fmaf(v2, bf2f(m2.x), fmaf(v1, bf2f(m1.x), fmaf(v0, bf2f(m0.x), AX)))))))); \
    AY = fmaf(v7, bf2f(m7.y), fmaf(v6, bf2f(m6.y), fmaf(v5, bf2f(m5.y), fmaf(v4, bf2f(m4.y), \
         fmaf(v3, bf2f(m3.y), fmaf(v2, bf2f(m2.y), fmaf(v1, bf2f(m1.y), fmaf(v0, bf2f(m0.y), AY)))))))); \
    AZ = fmaf(v7, bf2f(m7.z), fmaf(v6, bf2f(m6.z), fmaf(v5, bf2f(m5.z), fmaf(v4, bf2f(m4.z), \
         fmaf(v3, bf2f(m3.z), fmaf(v2, bf2f(m2.z), fmaf(v1, bf2f(m1.z), fmaf(v0, bf2f(m0.z), AZ)))))))); \
    AW = fmaf(v7, bf2f(m7.w), fmaf(v6, bf2f(m6.w), fmaf(v5, bf2f(m5.w), fmaf(v4, bf2f(m4.w), \
         fmaf(v3, bf2f(m3.w), fmaf(v2, bf2f(m2.w), fmaf(v1, bf2f(m1.w), fmaf(v0, bf2f(m0.w), AW)))))))); \
  }

// ---------------- private-LDS histogram -> slabs (128 blocks, no global atomics) ----
__global__ __launch_bounds__(256) void hist_priv_k(const int* __restrict__ rows,
                                                   const int* __restrict__ cols,
                                                   int* __restrict__ slabs) {
  __shared__ int cnt[8192];
  const int t = threadIdx.x;
  for (int i = t; i < 8192; i += 256) cnt[i] = 0;
  __syncthreads();
  int base = blockIdx.x * 1024;
  for (int i = t; i < 1024; i += 256) {
    int e = base + i;
    atomicAdd(&cnt[rows[e]], 1);
    atomicAdd(&cnt[4096 + cols[e]], 1);
  }
  __syncthreads();
  int* out = slabs + blockIdx.x * 8192;
  for (int i = t; i < 8192; i += 256) out[i] = cnt[i];
}

// ---------------- parallel slab reduce: 128 slabs -> sums[8192] ----------------
__global__ __launch_bounds__(256) void redslab_k(const int* __restrict__ slabs,
                                                 int* __restrict__ sums) {
  int bkt = blockIdx.x * 256 + threadIdx.x;   // 32 blocks x 256 = 8192
  int s = 0;
  for (int sl = 0; sl < 128; ++sl) s += slabs[sl * 8192 + bkt];
  sums[bkt] = s;
}

// ---------------- scan (sums -> rp/cp) + dtype detect + zero fills ------
__global__ __launch_bounds__(1024) void scan2_k(const unsigned int* __restrict__ X,
                                                const int* __restrict__ sums,
                                                int* __restrict__ rp, int* __restrict__ cp,
                                                int* __restrict__ rfill, int* __restrict__ cfill,
                                                int* __restrict__ flag) {
  __shared__ int part[1024];
  __shared__ int dcnt;
  const int t = threadIdx.x;
  if (t == 0) dcnt = 0;
  __syncthreads();
  int local = 0;
  for (int i = t; i < 4096; i += 1024) {
    unsigned e = (X[i] >> 7) & 0xFFu;
    if (e >= 100u && e <= 140u) local++;
  }
  if (local) atomicAdd(&dcnt, local);
  int base = t * 8, s = 0, loc[8];
  int csum[8];
#pragma unroll
  for (int j = 0; j < 8; ++j) csum[j] = sums[base + j];
#pragma unroll
  for (int j = 0; j < 8; ++j) { loc[j] = s; s += csum[j]; }
  part[t] = s;
  __syncthreads();
  if (t == 0) *flag = (dcnt > 2458) ? 1 : 0;
  for (int off = 1; off < 1024; off <<= 1) {
    int v = (t >= off) ? part[t - off] : 0;
    __syncthreads();
    part[t] += v;
    __syncthreads();
  }
  int excl = (t == 0) ? 0 : part[t - 1];
  int rtot = part[511];
  if (t < 512) {
#pragma unroll
    for (int j = 0; j < 8; ++j) rp[base + j] = excl + loc[j];
    if (t == 511) rp[4096] = rtot;
  } else {
    int cb = base - 4096;
    int ex2 = excl - rtot;
#pragma unroll
    for (int j = 0; j < 8; ++j) cp[cb + j] = ex2 + loc[j];
    if (t == 1023) cp[4096] = part[1023] - rtot;
  }
  for (int i = t; i < 4096; i += 1024) { rfill[i] = 0; cfill[i] = 0; }
}

// ---------------- converts/transposes + CSR/CSC scatter, one kernel ----------------
__global__ __launch_bounds__(256) void setup2_k(const void* __restrict__ X,
                                                const void* __restrict__ Wsh,
                                                const void* __restrict__ W0, const void* __restrict__ W1,
                                                const void* __restrict__ W2, const void* __restrict__ G0,
                                                const void* __restrict__ G1, const void* __restrict__ G2,
                                                const void* __restrict__ linW, const void* __restrict__ linb,
                                                const int* __restrict__ rows, const int* __restrict__ cols,
                                                const void* __restrict__ vals,
                                                const int* __restrict__ rp, const int* __restrict__ cp,
                                                int* __restrict__ rfill, int* __restrict__ cfill,
                                                int2* __restrict__ rpack, int2* __restrict__ cpack,
                                                u16* __restrict__ Xb, u16* __restrict__ WshT,
                                                u16* __restrict__ WTb, u16* __restrict__ WgTb,
                                                float* __restrict__ linWf, float* __restrict__ linbf,
                                                const int* __restrict__ flag) {
  int fl = *flag;
  int bx = blockIdx.x;
  if (bx >= 10245) {  // scatter part
    int e = (bx - 10245) * 256 + threadIdx.x;
    if (e >= NEd) return;
    float v = fl ? bf2f(((const u16*)vals)[e]) : ((const float*)vals)[e];
    int r = rows[e], c = cols[e];
    int p1 = rp[r] + atomicAdd(&rfill[r], 1);
    rpack[p1] = make_int2(c, __float_as_int(v));
    int p2 = cp[c] + atomicAdd(&cfill[c], 1);
    cpack[p2] = make_int2(r, __float_as_int(v));
    return;
  }
  int i = bx * 256 + threadIdx.x;
  if (i < 2097152) {
    Xb[i] = fl ? ((const u16*)X)[i] : f2bf(((const float*)X)[i]);
    return;
  }
  int i2 = i - 2097152;
  if (i2 < 131072) {
    int r = i2 >> 8, c = i2 & 255;
    u16 v = fl ? ((const u16*)Wsh)[i2] : f2bf(((const float*)Wsh)[i2]);
    WshT[c * 512 + r] = v;
    return;
  }
  int i3 = i2 - 131072;
  if (i3 < 393216) {
    int w = i3 >> 16, j = i3 & 65535;
    int r = j >> 8, c = j & 255;
    const void* src = (w == 0) ? W0 : (w == 1) ? W1 : (w == 2) ? W2
                     : (w == 3) ? G0 : (w == 4) ? G1 : G2;
    u16 v = fl ? ((const u16*)src)[j] : f2bf(((const float*)src)[j]);
    u16* dst = (w < 3) ? (WTb + w * 65536) : (WgTb + (w - 3) * 65536);
    dst[c * 256 + r] = v;
    return;
  }
  int i4 = i3 - 393216;
  if (i4 < 1024) { linWf[i4] = fl ? bf2f(((const u16*)linW)[i4]) : ((const float*)linW)[i4]; return; }
  if (i4 < 1026) { int k = i4 - 1024; linbf[k] = fl ? bf2f(((const u16*)linb)[k]) : ((const float*)linb)[k]; }
}

// ---------------- batched SpMM (CSR, int2 edges, bf16 gather, f32 accum) --------
// edge loop unrolled x8 (then x4, then singles): all loads of a group issued
// before its ordered FMAs; sequential fmaf nesting -> bit-identical sums.
struct SPP {
  const int* ptr; const int2* ep;
  const u16* m[3]; u16* ob[3]; unsigned long long oo[3];
};
__global__ __launch_bounds__(256) void spmm_mb_k(SPP s, const float* __restrict__ part,
                                                 void* __restrict__ outbase, int mode,
                                                 const int* __restrict__ flag) {
  const int b = blockIdx.y;
  int gid = blockIdx.x * 256 + threadIdx.x;
  int row = gid >> 6, lane = gid & 63, f = lane << 2;
  int beg = s.ptr[row], end = s.ptr[row + 1];
  const u16* m = s.m[b];
  float ax = 0.f, ay = 0.f, az = 0.f, aw = 0.f;
  int e = beg;
  for (; e + 7 < end; e += 8) GATH8(s.ep, m, f, ax, ay, az, aw, e);
  for (; e + 3 < end; e += 4) GATH4(s.ep, m, f, ax, ay, az, aw, e);
  for (; e < end; ++e) {
    int2 cv = s.ep[e];
    float v = __int_as_float(cv.y);
    ushort4 mv = *(const ushort4*)(m + (size_t)cv.x * HIDd + f);
    ax = fmaf(v, bf2f(mv.x), ax);
    ay = fmaf(v, bf2f(mv.y), ay);
    az = fmaf(v, bf2f(mv.z), az);
    aw = fmaf(v, bf2f(mv.w), aw);
  }
  size_t o = (size_t)row * HIDd + f;
  if (mode == 2) {
    const float* pb = part + (size_t)b * 1048576 + o;
    float4 p0 = *(const float4*)(pb);
    float4 p1 = *(const float4*)(pb + 3145728);
    float4 p2 = *(const float4*)(pb + 2 * 3145728);
    float4 p3 = *(const float4*)(pb + 3 * 3145728);
    ax += p0.x + p1.x + p2.x + p3.x;
    ay += p0.y + p1.y + p2.y + p3.y;
    az += p0.z + p1.z + p2.z + p3.z;
    aw += p0.w + p1.w + p2.w + p3.w;
    ax = fmaxf(ax, 0.f); ay = fmaxf(ay, 0.f);
    az = fmaxf(az, 0.f); aw = fmaxf(aw, 0.f);
    ushort4 o4 = { f2bf(ax), f2bf(ay), f2bf(az), f2bf(aw) };
    *(ushort4*)(s.ob[b] + o) = o4;
    if (*flag) *(ushort4*)((u16*)outbase + s.oo[b] + o) = o4;
    else       *(float4*)((float*)outbase + s.oo[b] + o) = make_float4(ax, ay, az, aw);
  } else {
    if (mode == 0) {
      ax = fmaxf(ax, 0.f); ay = fmaxf(ay, 0.f);
      az = fmaxf(az, 0.f); aw = fmaxf(aw, 0.f);
    }
    ushort4 o4 = { f2bf(ax), f2bf(ay), f2bf(az), f2bf(aw) };
    *(ushort4*)(s.ob[b] + o) = o4;
  }
}

// ---------------- redt only (tT partial reduce) ----------------
__global__ __launch_bounds__(256) void redt_k(const float* __restrict__ part,
                                              u16* __restrict__ tT) {
  int i = (blockIdx.x * 256 + threadIdx.x) * 4;
  float4 s0 = *(const float4*)(part + i);
  float4 s1 = *(const float4*)(part + i + 3145728);
  float4 s2 = *(const float4*)(part + i + 2 * 3145728);
  float4 s3 = *(const float4*)(part + i + 3 * 3145728);
  ushort4 o = { f2bf(s0.x + s1.x + s2.x + s3.x), f2bf(s0.y + s1.y + s2.y + s3.y),
                f2bf(s0.z + s1.z + s2.z + s3.z), f2bf(s0.w + s1.w + s2.w + s3.w) };
  *(ushort4*)(tT + i) = o;
}

// ---------------- tall-tile split-K GEMM + fused spmm-u (J4) ------
// blockIdx.x <  128 : tall GEMM (J4/J5 structure, unchanged arithmetic)
// blockIdx.x >= 128 : CSC spmm-u gather blocks (512 thr = 8 rows), J4 launch only.
// The gather depends only on hp (ready before this dispatch) -> overlaps MFMA.
struct TQ {
  const u16* Ap[3]; const u16* Bp[3]; unsigned long long c0[3];
  int tallA, K, N, kspan;
  const int* cp; const int2* cep;
  const u16* hp[3]; u16* ub[3];
};

__global__ __launch_bounds__(512) void tall_spmmu_k(TQ P, float* __restrict__ partf) {
  __shared__ __align__(16) u16 smem[24576];   // 48 KB
  const int b = blockIdx.z;
  const int bx = blockIdx.x;
  if (bx >= 128) {
    // ---- fused spmm-u: u_b = A^T @ hp_b (CSC), bf16 store ----
    int gid = (bx - 128) * 512 + threadIdx.x;
    int row = gid >> 6, lane = gid & 63, f = lane << 2;
    int beg = P.cp[row], end = P.cp[row + 1];
    const u16* m = P.hp[b];
    float ax = 0.f, ay = 0.f, az = 0.f, aw = 0.f;
    int e = beg;
    for (; e + 3 < end; e += 4) GATH4(P.cep, m, f, ax, ay, az, aw, e);
    for (; e < end; ++e) {
      int2 cv = P.cep[e];
      float v = __int_as_float(cv.y);
      ushort4 mv = *(const ushort4*)(m + (size_t)cv.x * HIDd + f);
      ax = fmaf(v, bf2f(mv.x), ax);
      ay = fmaf(v, bf2f(mv.y), ay);
      az = fmaf(v, bf2f(mv.z), az);
      aw = fmaf(v, bf2f(mv.w), aw);
    }
    size_t o = (size_t)row * HIDd + f;
    ushort4 o4 = { f2bf(ax), f2bf(ay), f2bf(az), f2bf(aw) };
    *(ushort4*)(P.ub[b] + o) = o4;
    return;
  }
  // ---- tall GEMM ----
  const u16* A = P.Ap[b];
  const u16* B = P.Bp[b];
  const int K = P.K, N = P.N, tallA = P.tallA;
  const int stripe = bx & 31, ks = bx >> 5;
  const int tid = threadIdx.x, w = tid >> 6, lane = tid & 63;
  const int lr = lane >> 3, cc = lane & 7;
  const int scol = (cc ^ lr) << 3;
  u16* As = smem;
  u16* Bs = smem + (tallA ? 16384 : 8192);
  int wrow, wcol;
  if (tallA) { wrow = (w >> 1) * 64; wcol = (w & 1) * 64; }
  else       { wrow = (w >> 2) * 64; wcol = (w & 3) * 64; }
  const int row0 = tallA ? 0 : stripe * 128;
  const int col0 = tallA ? stripe * 128 : 0;
  const int na = tallA ? 4 : 2;   // A chunks (1 KB) per wave
  const int nb = tallA ? 2 : 4;   // B chunks per wave
  floatx4 acc[4][4] = {};
  int aoff[4], boff[4];
#pragma unroll
  for (int i = 0; i < 4; ++i) {
    int m = wrow + i * 16 + (lane & 15);        // local A row
    aoff[i] = m * 64 + (((lane >> 4) << 3) ^ ((m & 7) << 3));
    int n = wcol + i * 16 + (lane & 15);        // local B row
    boff[i] = n * 64 + (((lane >> 4) << 3) ^ ((n & 7) << 3));
  }
  const int kbeg = ks * P.kspan, kend = kbeg + P.kspan;
  for (int k0 = kbeg; k0 < kend; k0 += 64) {
#pragma unroll
    for (int t = 0; t < 4; ++t) {
      if (t < na) {
        int ch = na * w + t;
        GLDS(A + (size_t)(row0 + 8 * ch + lr) * K + k0 + scol, As + ch * 512);
      }
      if (t < nb) {
        int ch = nb * w + t;
        GLDS(B + (size_t)(col0 + 8 * ch + lr) * K + k0 + scol, Bs + ch * 512);
      }
    }
    __syncthreads();
#pragma unroll
    for (int kk = 0; kk < 2; ++kk) {
      bf16x8 af[4], bfr[4];
#pragma unroll
      for (int i = 0; i < 4; ++i) {
        af[i]  = *(const bf16x8*)(As + (aoff[i] ^ (kk << 5)));
        bfr[i] = *(const bf16x8*)(Bs + (boff[i] ^ (kk << 5)));
      }
#pragma unroll
      for (int i = 0; i < 4; ++i)
#pragma unroll
        for (int j = 0; j < 4; ++j)
          acc[i][j] = __builtin_amdgcn_mfma_f32_16x16x32_bf16(af[i], bfr[j], acc[i][j], 0, 0, 0);
    }
    __syncthreads();
  }
  const int l15 = lane & 15, q4 = (lane >> 4) << 2;
  float* C = partf + P.c0[b] + (size_t)ks * 3145728;
  const int cbase = col0 + wcol + l15;
#pragma unroll
  for (int i = 0; i < 4; ++i)
#pragma unroll
    for (int r = 0; r < 4; ++r) {
      size_t rb = (size_t)(row0 + wrow + i * 16 + q4 + r) * N + cbase;
#pragma unroll
      for (int j = 0; j < 4; ++j) C[rb + j * 16] = acc[i][j][r];
    }
}

// ---------------- job-table bf16 MFMA NT GEMM ----------------
// modes: 0 bf16->ws; 1 sigmoid->bf16 d_out; 3 adaptive d_out; 4 dual bf16->ws;
//        6 head (log_softmax). sym: upper tiles + mirror.
struct Job {
  const u16* A; const u16* B;
  const float* F1; const float* F2;
  unsigned long long c0, c1, pstride;
  int M, N, K, mode, xt, ntiles, nks, kspan, sym;
};
struct Jobs { Job j[6]; };

__global__ __launch_bounds__(256) void gemm_mega(Jobs P, void* __restrict__ WSv,
                                                 void* __restrict__ OutO,
                                                 const int* __restrict__ flag) {
  __shared__ __align__(16) u16 smem[17408];
  u16* As = smem;
  u16* Bs = smem + 8192;
  u16* Ts = smem;
  const Job jb = P.j[blockIdx.z];
  const unsigned tile = blockIdx.x;
  if ((int)tile >= jb.ntiles * jb.nks) return;
  if (jb.mode == 6) {  // head: pred_T = log_softmax([ziv|zc] @ lw + lb)
    int i = tile * 256 + threadIdx.x;
    const float* lw = jb.F1;
    float a0 = jb.F2[0], a1 = jb.F2[1];
    for (int f = 0; f < HIDd; ++f) {
      float zv = bf2f(jb.A[(size_t)i * HIDd + f]);
      a0 = fmaf(zv, lw[2 * f + 0], a0);
      a1 = fmaf(zv, lw[2 * f + 1], a1);
    }
    for (int f = 0; f < HIDd; ++f) {
      float zv = bf2f(jb.B[(size_t)i * HIDd + f]);
      a0 = fmaf(zv, lw[2 * (HIDd + f) + 0], a0);
      a1 = fmaf(zv, lw[2 * (HIDd + f) + 1], a1);
    }
    float mx = fmaxf(a0, a1);
    float lse = mx + logf(expf(a0 - mx) + expf(a1 - mx));
    float p0 = a0 - lse, p1 = a1 - lse;
    if (*flag) {
      u16* ob = (u16*)OutO;
      ob[jb.c0 + 2 * i + 0] = f2bf(p0);
      ob[jb.c0 + 2 * i + 1] = f2bf(p1);
      if (i == 0) ob[jb.c1] = 0;
    } else {
      float* ob = (float*)OutO;
      ob[jb.c0 + 2 * i + 0] = p0;
      ob[jb.c0 + 2 * i + 1] = p1;
      if (i == 0) ob[jb.c1] = 0.f;
    }
    return;
  }
  const unsigned ks = tile / (unsigned)jb.ntiles;
  const unsigned t2 = tile - ks * jb.ntiles;
  unsigned ty, tx;
  if (jb.sym) {
    unsigned rem = t2, rowlen = jb.xt; ty = 0;
    while (rem >= rowlen) { rem -= rowlen; --rowlen; ++ty; }
    tx = ty + rem;
  } else {
    ty = t2 / (unsigned)jb.xt;
    tx = t2 - ty * jb.xt;
  }
  const int K = jb.K, N = jb.N;
  const int row0 = ty * 128, col0 = tx * 128;
  const int tid = threadIdx.x;
  const int w = tid >> 6, lane = tid & 63;
  const int wr = (w >> 1) * 64, wc = (w & 1) * 64;
  const int lr = lane >> 3, cc = lane & 7;
  const int scol = (cc ^ lr) << 3;
  floatx4 acc[4][4] = {};
  int aoff[4], boff[4];
#pragma unroll
  for (int i = 0; i < 4; ++i) {
    int m = wr + i * 16 + (lane & 15);
    aoff[i] = m * 64 + ((((lane >> 4) << 3)) ^ ((m & 7) << 3));
    int n = wc + i * 16 + (lane & 15);
    boff[i] = n * 64 + ((((lane >> 4) << 3)) ^ ((n & 7) << 3));
  }
  const u16* A = jb.A;
  const u16* B = jb.B;
  const int kbeg = ks * jb.kspan, kend = kbeg + jb.kspan;
  for (int k0 = kbeg; k0 < kend; k0 += 64) {
#pragma unroll
    for (int t = 0; t < 4; ++t) {
      int ch = 4 * w + t;
      GLDS(A + (size_t)(row0 + 8 * ch + lr) * K + k0 + scol, As + ch * 512);
      GLDS(B + (size_t)(col0 + 8 * ch + lr) * K + k0 + scol, Bs + ch * 512);
    }
    __syncthreads();
#pragma unroll
    for (int kk = 0; kk < 2; ++kk) {
      bf16x8 af[4], bfr[4];
#pragma unroll
      for (int i = 0; i < 4; ++i) {
        af[i]  = *(const bf16x8*)(As + (aoff[i] ^ (kk << 5)));
        bfr[i] = *(const bf16x8*)(Bs + (boff[i] ^ (kk << 5)));
      }
#pragma unroll
      for (int i = 0; i < 4; ++i)
#pragma unroll
        for (int j = 0; j < 4; ++j)
          acc[i][j] = __builtin_amdgcn_mfma_f32_16x16x32_bf16(af[i], bfr[j], acc[i][j], 0, 0, 0);
    }
    __syncthreads();
  }

  const int l15 = lane & 15, q4 = (lane >> 4) << 2;
  const int cb = col0 + wc + l15;
  const int mode = jb.mode;
  if (mode == 0 || mode == 1) {
    u16* C = ((mode == 1) ? (u16*)OutO : (u16*)WSv) + jb.c0;
#pragma unroll
    for (int i = 0; i < 4; ++i)
#pragma unroll
      for (int r = 0; r < 4; ++r) {
        int lrow = wr + i * 16 + q4 + r;
        size_t rb = (size_t)(row0 + lrow) * N + cb;
#pragma unroll
        for (int j = 0; j < 4; ++j) {
          float v = acc[i][j][r];
          if (mode == 1) v = 1.f / (1.f + __expf(-v));
          u16 vb = f2bf(v);
          C[rb + j * 16] = vb;
          if (jb.sym) Ts[(wc + j * 16 + l15) * 136 + lrow] = vb;
        }
      }
    if (jb.sym && tx != ty) {
      __syncthreads();
      int rr = tid >> 1, hf = (tid & 1) << 6;
      size_t rb2 = (size_t)(col0 + rr) * N + row0 + hf;
#pragma unroll
      for (int k = 0; k < 8; ++k)
        *(uint4*)(C + rb2 + k * 8) = *(const uint4*)(Ts + rr * 136 + hf + k * 8);
    }
  } else if (mode == 4) {
    u16* C  = (u16*)WSv + jb.c0;
    u16* CT = (u16*)WSv + jb.c1;
    const int M = jb.M;
#pragma unroll
    for (int i = 0; i < 4; ++i)
#pragma unroll
      for (int r = 0; r < 4; ++r) {
        int gr = row0 + wr + i * 16 + q4 + r;
#pragma unroll
        for (int j = 0; j < 4; ++j) {
          u16 v = f2bf(acc[i][j][r]);
          int gc = cb + j * 16;
          C[(size_t)gr * N + gc] = v;
          CT[(size_t)gc * M + gr] = v;
        }
      }
  } else {  // mode 3: adaptive dtype store into d_out
    if (*flag) {
      u16* C = (u16*)OutO + jb.c0;
#pragma unroll
      for (int i = 0; i < 4; ++i)
#pragma unroll
        for (int r = 0; r < 4; ++r) {
          int lrow = wr + i * 16 + q4 + r;
          size_t rb = (size_t)(row0 + lrow) * N + cb;
#pragma unroll
          for (int j = 0; j < 4; ++j) {
            u16 vb = f2bf(acc[i][j][r]);
            C[rb + j * 16] = vb;
            if (jb.sym) Ts[(wc + j * 16 + l15) * 136 + lrow] = vb;
          }
        }
      if (jb.sym && tx != ty) {
        __syncthreads();
        int rr = tid >> 1, hf = (tid & 1) << 6;
        size_t rb2 = (size_t)(col0 + rr) * N + row0 + hf;
#pragma unroll
        for (int k = 0; k < 8; ++k)
          *(uint4*)(C + rb2 + k * 8) = *(const uint4*)(Ts + rr * 136 + hf + k * 8);
      }
    } else {
      float* C = (float*)OutO + jb.c0;
      // direct (upper-triangle) tile: coalesced 64B quarter-wave stores
#pragma unroll
      for (int i = 0; i < 4; ++i)
#pragma unroll
      for (int r = 0; r < 4; ++r) {
          int gr = row0 + wr + i * 16 + q4 + r;
          size_t rb = (size_t)gr * N + cb;
#pragma unroll
          for (int j = 0; j < 4; ++j) C[rb + j * 16] = acc[i][j][r];
        }
      // mirror tile: LDS-staged f32 transpose in two 64-column half-passes,
      // then fully-coalesced 128-float row writes.
      if (jb.sym && tx != ty) {
        float* Tf = (float*)smem;          // 64 x 132 f32 = 33792 B <= 34816 B
        const int whalf = w & 1;           // wave's column half (wc = whalf*64)
#pragma unroll
        for (int half = 0; half < 2; ++half) {
          __syncthreads();                  // smem (As/Bs or prev half) dead
          if (whalf == half) {
#pragma unroll
            for (int i = 0; i < 4; ++i)
#pragma unroll
              for (int j = 0; j < 4; ++j) {
                int cl = j * 16 + l15;      // column-local within this half
#pragma unroll
                for (int r = 0; r < 4; ++r)
                  Tf[cl * 132 + wr + i * 16 + q4 + r] = acc[i][j][r];
              }
          }
          __syncthreads();
          int cl = tid >> 2, chf = (tid & 3) << 5;   // 4 threads per row, 32 f ea
          size_t rb2 = (size_t)(col0 + half * 64 + cl) * N + row0 + chf;
          const float* src = Tf + cl * 132 + chf;
#pragma unroll
          for (int k = 0; k < 8; ++k)
            *(float4*)(C + rb2 + k * 4) = *(const float4*)(src + k * 4);
        }
      }
    }
  }
}

// =======================================================================
extern "C" void kernel_launch(void* const* d_in, const int* in_sizes, int n_in,
                              void* d_out, int out_size, void* d_ws, size_t ws_size,
                              hipStream_t stream) {
  const void* X    = d_in[0];
  const int*  rows = (const int*)d_in[1];
  const int*  cols = (const int*)d_in[2];
  const void* vals = d_in[3];
  const void* Wsh  = d_in[4];

  char* W = (char*)d_ws;
  u16*  Xb    = (u16*)(W + 0);
  u16*  WshT  = (u16*)(W + 4194304);
  u16*  WTb   = (u16*)(W + 4456448);
  u16*  WgTb  = (u16*)(W + 4849664);
  int*  rp    = (int*)(W + 5242880);
  int*  cp    = (int*)(W + 5275648);
  int*  rfill = (int*)(W + 5308416);
  int*  cfill = (int*)(W + 5324800);
  int2* rpack = (int2*)(W + 5341184);   // 1 MB
  int2* cpack = (int2*)(W + 6389760);   // 1 MB
  float* linWf = (float*)(W + 7438336);
  float* linbf = (float*)(W + 7442432);
  int*  flag  = (int*)(W + 7442560);
  u16*  hb    = (u16*)(W + 8388608);
  u16*  tmpb[3] = { (u16*)(W + 10485760), (u16*)(W + 12582912), (u16*)(W + 14680064) };
  u16*  z0b[3]  = { (u16*)(W + 16777216), (u16*)(W + 18874368), (u16*)(W + 20971520) };
  u16*  hpb[3]  = { (u16*)(W + 23068672), (u16*)(W + 25165824), (u16*)(W + 27262976) };
  u16*  hpT[3]  = { (u16*)(W + 29360128), (u16*)(W + 31457280), (u16*)(W + 33554432) };
  u16*  tTb     = (u16*)(W + 35651584);
  u16*  zbb[3]  = { (u16*)(W + 41943040), (u16*)(W + 44040192), (u16*)(W + 46137344) };
  u16*  ubb[3]  = { (u16*)(W + 48234496), (u16*)(W + 50331648), (u16*)(W + 52428800) };
  float* partf  = (float*)(W + 54525952);   // 48 MB split-K partials (also hist slabs)
  int*  slabs  = (int*)(W + 54525952);      // 4 MB (128 slabs), consumed before partials
  int*  sums   = (int*)(W + 54525952 + 4194304);  // 32 KB bucket sums

  const long long z_off[3]   = { 0LL, 17825792LL, 35651584LL };
  const long long rec_off[3] = { 1048576LL, 18874368LL, 36700160LL };
  const long long mi_off = 53477376LL, pred_off = 53477377LL;

  const u16* r2p[3] = { (const u16*)d_out + rec_off[0], (const u16*)d_out + rec_off[1],
                        (const u16*)d_out + rec_off[2] };

  // 1. private-LDS histograms -> 128 slabs (4x parallelism)
  hist_priv_k<<<128, 256, 0, stream>>>(rows, cols, slabs);
  // 1b. parallel slab reduce -> sums[8192]
  redslab_k<<<32, 256, 0, stream>>>(slabs, sums);
  // 2. scan (32 KB read) + dtype detect + zero fills
  scan2_k<<<1, 1024, 0, stream>>>((const unsigned int*)X, sums, rp, cp, rfill, cfill, flag);
  // 3. converts/transposes + scatter
  setup2_k<<<10757, 256, 0, stream>>>(X, Wsh, d_in[5], d_in[6], d_in[7],
                                      d_in[8], d_in[9], d_in[10], d_in[11], d_in[12],
                                      rows, cols, vals, rp, cp, rfill, cfill, rpack, cpack,
                                      Xb, WshT, WTb, WgTb, linWf, linbf, flag);

  Jobs P{};
  auto setj = [](Job& j, const u16* A, const u16* B, unsigned long long c0,
                 unsigned long long c1, unsigned long long ps, int M, int N, int K,
                 int mode, int nks, int sym) {
    j.A = A; j.B = B; j.F1 = nullptr; j.F2 = nullptr;
    j.c0 = c0; j.c1 = c1; j.pstride = ps;
    j.M = M; j.N = N; j.K = K; j.mode = mode;
    j.xt = N / 128;
    j.ntiles = sym ? (j.xt * (j.xt + 1)) / 2 : (M / 128) * (N / 128);
    j.nks = nks; j.kspan = K / nks; j.sym = sym;
  };

  // 4. J1: tmp0 = X @ Wsh
  setj(P.j[0], Xb, WshT, ((char*)tmpb[0] - W) / 2, 0, 0, Nn, HIDd, FINd, 0, 1, 0);
  gemm_mega<<<dim3(64, 1, 1), 256, 0, stream>>>(P, d_ws, d_out, flag);

  // 5. h = relu(A @ tmp0)
  SPP s{};
  s.ptr = rp; s.ep = rpack;
  s.m[0] = tmpb[0]; s.ob[0] = hb;
  spmm_mb_k<<<dim3(Nn / 4, 1), 256, 0, stream>>>(s, nullptr, nullptr, 0, flag);

  // 6. J2: tmp_b = h @ W_b
  for (int b = 0; b < 3; ++b)
    setj(P.j[b], hb, WTb + b * 65536, ((char*)tmpb[b] - W) / 2, 0, 0, Nn, HIDd, HIDd, 0, 1, 0);
  gemm_mega<<<dim3(64, 1, 3), 256, 0, stream>>>(P, d_ws, d_out, flag);

  // 7. z0_b = relu(A @ tmp_b)
  for (int b = 0; b < 3; ++b) { s.m[b] = tmpb[b]; s.ob[b] = z0b[b]; }
  spmm_mb_k<<<dim3(Nn / 4, 3), 256, 0, stream>>>(s, nullptr, nullptr, 0, flag);

  // 8. J3: r2_b = sigmoid(z0 z0^T) [SYM] + hp_b = z0 @ Wg_b [dual]
  for (int b = 0; b < 3; ++b) {
    setj(P.j[b], z0b[b], z0b[b], rec_off[b], 0, 0, Nn, Nn, HIDd, 1, 1, 1);
    setj(P.j[3 + b], z0b[b], WgTb + b * 65536, ((char*)hpb[b] - W) / 2,
         ((char*)hpT[b] - W) / 2, 0, Nn, HIDd, HIDd, 4, 1, 0);
  }
  gemm_mega<<<dim3(528, 1, 6), 256, 0, stream>>>(P, d_ws, d_out, flag);

  // 9. J4 (tall-A) + fused spmm-u: tT partials = h'^T @ r2 (128 blocks)
  //    + u_b = A^T @ hp_b (512 CSC gather blocks, overlap MFMA)
  TQ T{};
  for (int b = 0; b < 3; ++b) {
    T.Ap[b] = hpT[b]; T.Bp[b] = r2p[b];
    T.c0[b] = (unsigned long long)b * 1048576ULL;
    T.hp[b] = hpb[b]; T.ub[b] = ubb[b];
  }
  T.tallA = 1; T.K = Nn; T.N = Nn; T.kspan = 1024;
  T.cp = cp; T.cep = cpack;
  tall_spmmu_k<<<dim3(640, 1, 3), 512, 0, stream>>>(T, partf);

  // 10. redt (tT partials -> bf16)
  redt_k<<<3072, 256, 0, stream>>>(partf, tTb);

  // 11. J5 (tall-B): buf partials = r2 @ t, split-K=4 (no fused gather)
  TQ T2{};
  for (int b = 0; b < 3; ++b) {
    T2.Ap[b] = r2p[b]; T2.Bp[b] = tTb + b * 1048576;
    T2.c0[b] = (unsigned long long)b * 1048576ULL;
    T2.hp[b] = nullptr; T2.ub[b] = nullptr;
  }
  T2.tallA = 0; T2.K = Nn; T2.N = HIDd; T2.kspan = 1024;
  T2.cp = nullptr; T2.cep = nullptr;
  tall_spmmu_k<<<dim3(128, 1, 3), 512, 0, stream>>>(T2, partf);

  // 12. z_b = relu(sum4(buf parts) + A @ u_b) -> zbb + d_out
  for (int b = 0; b < 3; ++b) {
    s.m[b] = ubb[b];
    s.ob[b] = zbb[b]; s.oo[b] = (unsigned long long)z_off[b];
  }
  spmm_mb_k<<<dim3(Nn / 4, 3), 256, 0, stream>>>(s, partf, d_out, 2, flag);

  // 13. J6: zrec_b = z z^T -> d_out [SYM, adaptive] + head [mode 6]
  for (int b = 0; b < 3; ++b)
    setj(P.j[b], zbb[b], zbb[b], rec_off[b], 0, 0, Nn, Nn, HIDd, 3, 1, 1);
  setj(P.j[3], zbb[0], zbb[1], (unsigned long long)pred_off,
       (unsigned long long)mi_off, 0, 256, 128, 64, 6, 1, 0);
  P.j[3].ntiles = 16; P.j[3].nks = 1;
  P.j[3].F1 = linWf; P.j[3].F2 = linbf;
  gemm_mega<<<dim3(528, 1, 4), 256, 0, stream>>>(P, d_ws, d_out, flag);

  (void)in_sizes; (void)n_in; (void)out_size; (void)ws_size;
}